// Round 3
// baseline (524.859 us; speedup 1.0000x reference)
//
#include <hip/hip_runtime.h>

typedef unsigned short u16;
typedef __bf16 bf16_t;
typedef bf16_t bf16x8 __attribute__((ext_vector_type(8)));
typedef u16 u16x8 __attribute__((ext_vector_type(8)));
typedef float f32x4 __attribute__((ext_vector_type(4)));

__device__ __forceinline__ float bf2f(u16 u) {
    union { float f; unsigned i; } c; c.i = ((unsigned)u) << 16; return c.f;
}
__device__ __forceinline__ u16 f2bf(float f) {
    union { float f; unsigned i; } c; c.f = f;
    unsigned i = c.i;
    unsigned r = i + 0x7FFFu + ((i >> 16) & 1u);
    return (u16)(r >> 16);
}
__device__ __forceinline__ f32x4 mfma16(bf16x8 a, bf16x8 b, f32x4 c) {
    return __builtin_amdgcn_mfma_f32_16x16x32_bf16(a, b, c, 0, 0, 0);
}

// ---------------------------------------------------------------------------
// f32 -> bf16 conversion, 8 elems/thread, exact grid (n % 2048 == 0)
// ---------------------------------------------------------------------------
__global__ __launch_bounds__(256)
void cvt_kernel(const float* __restrict__ in, u16* __restrict__ out)
{
    const int i = (blockIdx.x * 256 + threadIdx.x) * 8;
    float4 a = *reinterpret_cast<const float4*>(in + i);
    float4 b = *reinterpret_cast<const float4*>(in + i + 4);
    u16x8 o;
    o[0] = f2bf(a.x); o[1] = f2bf(a.y); o[2] = f2bf(a.z); o[3] = f2bf(a.w);
    o[4] = f2bf(b.x); o[5] = f2bf(b.y); o[6] = f2bf(b.z); o[7] = f2bf(b.w);
    *reinterpret_cast<u16x8*>(out + i) = o;
}

// ---------------------------------------------------------------------------
// GEMM: C[M,N] = A[M,K] @ B[K,N]; A bf16; B bf16 or f32 (converted in staging);
// bias f32. C bf16. 128x128 tile, BK=32, 4 waves 2x2, each wave 64x64.
// ---------------------------------------------------------------------------
template<bool BIAS, bool RELU, bool BF32>
__global__ __launch_bounds__(256)
void gemm_kernel(const u16* __restrict__ A, const void* __restrict__ Bp,
                 const float* __restrict__ bias, u16* __restrict__ C,
                 int M, int N, int K)
{
    __shared__ u16 As[128][32];
    __shared__ u16 Bs[32][128];
    const int tid  = threadIdx.x;
    const int lane = tid & 63;
    const int wid  = tid >> 6;
    const int wm = wid >> 1, wn = wid & 1;
    const int bm = blockIdx.x, bn = blockIdx.y;
    const int kg = lane >> 4;   // 0..3
    const int lc = lane & 15;

    f32x4 acc[4][4];
    #pragma unroll
    for (int i = 0; i < 4; ++i)
        #pragma unroll
        for (int j = 0; j < 4; ++j)
            acc[i][j] = f32x4{0.f, 0.f, 0.f, 0.f};

    const int nk = K >> 5;
    for (int kt = 0; kt < nk; ++kt) {
        __syncthreads();
        // stage A tile 128x32 (bf16, 512 x 16B chunks)
        #pragma unroll
        for (int p = 0; p < 2; ++p) {
            int c = tid + p * 256;
            int row = c >> 2, ch = c & 3;
            *reinterpret_cast<uint4*>(&As[row][ch * 8]) =
                *reinterpret_cast<const uint4*>(&A[(size_t)(bm * 128 + row) * K + kt * 32 + ch * 8]);
        }
        // stage B tile 32x128
        if constexpr (BF32) {
            const float* B = (const float*)Bp;
            #pragma unroll
            for (int p = 0; p < 4; ++p) {
                int c = tid + p * 256;
                int row = c >> 5, ch = c & 31;
                float4 bv = *reinterpret_cast<const float4*>(
                    &B[(size_t)(kt * 32 + row) * N + bn * 128 + ch * 4]);
                ushort4 st;
                st.x = f2bf(bv.x); st.y = f2bf(bv.y); st.z = f2bf(bv.z); st.w = f2bf(bv.w);
                *reinterpret_cast<ushort4*>(&Bs[row][ch * 4]) = st;
            }
        } else {
            const u16* B = (const u16*)Bp;
            #pragma unroll
            for (int p = 0; p < 2; ++p) {
                int c = tid + p * 256;
                int row = c >> 4, ch = c & 15;
                *reinterpret_cast<uint4*>(&Bs[row][ch * 8]) =
                    *reinterpret_cast<const uint4*>(&B[(size_t)(kt * 32 + row) * N + bn * 128 + ch * 8]);
            }
        }
        __syncthreads();

        bf16x8 af[4];
        #pragma unroll
        for (int i = 0; i < 4; ++i)
            af[i] = *reinterpret_cast<const bf16x8*>(&As[wm * 64 + i * 16 + lc][kg * 8]);

        #pragma unroll
        for (int j = 0; j < 4; ++j) {
            int col = wn * 64 + j * 16 + lc;
            u16x8 bt;
            #pragma unroll
            for (int e = 0; e < 8; ++e) bt[e] = Bs[kg * 8 + e][col];
            bf16x8 bfr = __builtin_bit_cast(bf16x8, bt);
            #pragma unroll
            for (int i = 0; i < 4; ++i)
                acc[i][j] = mfma16(af[i], bfr, acc[i][j]);
        }
    }

    #pragma unroll
    for (int i = 0; i < 4; ++i) {
        #pragma unroll
        for (int j = 0; j < 4; ++j) {
            int col = bn * 128 + wn * 64 + j * 16 + lc;
            float bv = 0.f;
            if (BIAS) bv = bias[col];
            #pragma unroll
            for (int r = 0; r < 4; ++r) {
                int row = bm * 128 + wm * 64 + i * 16 + kg * 4 + r;
                float v = acc[i][j][r] + bv;
                if (RELU) v = v > 0.f ? v : 0.f;
                C[(size_t)row * N + col] = f2bf(v);
            }
        }
    }
}

// ---------------------------------------------------------------------------
// segment ids: seg[b, s] = inclusive cumsum(tokens == start_id)
// ---------------------------------------------------------------------------
__global__ __launch_bounds__(256)
void seg_kernel(const int* __restrict__ tokens, const int* __restrict__ start_id,
                int* __restrict__ seg)
{
    constexpr int S = 2048;
    __shared__ int part[256];
    __shared__ int pref[256];
    const int b = blockIdx.x, tid = threadIdx.x;
    const int sid = start_id[0];
    const int base = b * S + tid * 8;
    int f[8]; int loc = 0;
    #pragma unroll
    for (int j = 0; j < 8; ++j) { f[j] = (tokens[base + j] == sid) ? 1 : 0; loc += f[j]; }
    part[tid] = loc;
    __syncthreads();
    if (tid == 0) {
        int run = 0;
        for (int i = 0; i < 256; ++i) { pref[i] = run; run += part[i]; }
    }
    __syncthreads();
    int run = pref[tid];
    #pragma unroll
    for (int j = 0; j < 8; ++j) { run += f[j]; seg[base + j] = run; }
}

// ---------------------------------------------------------------------------
// flash attention, causal + segment mask.  grid (S/64, H, B), 256 thr = 4 waves
// wave w handles 16 query rows; K/V tiles of 64 staged in LDS.
// Mask levels: masked score = -60000, m init = -30000 -> masked p = exp(<=-30000)=0
// in every case (virgin-max + fully-masked tile included); all exp args finite <=0.
// ---------------------------------------------------------------------------
#define MASKVAL -60000.0f
#define MINIT   -30000.0f
__global__ __launch_bounds__(256)
void attn_kernel(const u16* __restrict__ qkv, const int* __restrict__ seg,
                 u16* __restrict__ attn_out)
{
    constexpr int S = 2048, DQ = 3072;
    __shared__ u16 Ks[64][64];
    __shared__ u16 Vs[64][64];
    __shared__ u16 Ps[4][16][64];
    __shared__ int segk[64];

    const int tid = threadIdx.x;
    const int lane = tid & 63, w = tid >> 6;
    const int kg = lane >> 4, lc = lane & 15;
    const int qt = blockIdx.x, h = blockIdx.y, b = blockIdx.z;
    const size_t rowbase = (size_t)b * S;
    const int qbase = qt * 64;
    const int colK = h * 192, colQ = colK + 64, colV = colK + 128;

    // Q fragments for this wave's 16 rows (HD=64 -> 2 k-slices)
    bf16x8 qf[2];
    {
        const u16* qp = &qkv[(rowbase + qbase + w * 16 + lc) * DQ + colQ];
        qf[0] = *reinterpret_cast<const bf16x8*>(qp + kg * 8);
        qf[1] = *reinterpret_cast<const bf16x8*>(qp + 32 + kg * 8);
    }
    int qg[4], sq[4];
    float m_[4], l_[4];
    f32x4 o[4];
    #pragma unroll
    for (int r = 0; r < 4; ++r) {
        qg[r] = qbase + w * 16 + kg * 4 + r;
        sq[r] = seg[rowbase + qg[r]];
        m_[r] = MINIT; l_[r] = 0.f;
    }
    #pragma unroll
    for (int d = 0; d < 4; ++d) o[d] = f32x4{0.f, 0.f, 0.f, 0.f};

    for (int kb = 0; kb <= qt; ++kb) {
        __syncthreads();
        #pragma unroll
        for (int p = 0; p < 2; ++p) {
            int c = tid + p * 256;
            int row = c >> 3, ch = c & 7;
            const size_t gr = (rowbase + (size_t)kb * 64 + row) * DQ;
            *reinterpret_cast<uint4*>(&Ks[row][ch * 8]) =
                *reinterpret_cast<const uint4*>(&qkv[gr + colK + ch * 8]);
            *reinterpret_cast<uint4*>(&Vs[row][ch * 8]) =
                *reinterpret_cast<const uint4*>(&qkv[gr + colV + ch * 8]);
        }
        if (tid < 64) segk[tid] = seg[rowbase + kb * 64 + tid];
        __syncthreads();

        // S = Q K^T  (4 key sub-tiles of 16)
        f32x4 sc[4];
        #pragma unroll
        for (int ks = 0; ks < 4; ++ks) {
            bf16x8 kf0 = *reinterpret_cast<const bf16x8*>(&Ks[ks * 16 + lc][kg * 8]);
            bf16x8 kf1 = *reinterpret_cast<const bf16x8*>(&Ks[ks * 16 + lc][32 + kg * 8]);
            f32x4 s = f32x4{0.f, 0.f, 0.f, 0.f};
            s = mfma16(qf[0], kf0, s);
            s = mfma16(qf[1], kf1, s);
            sc[ks] = s;
        }
        // mask + scale (1/sqrt(64) = 0.125)
        #pragma unroll
        for (int ks = 0; ks < 4; ++ks) {
            int kidx = kb * 64 + ks * 16 + lc;
            int sk = segk[ks * 16 + lc];
            #pragma unroll
            for (int r = 0; r < 4; ++r) {
                bool ok = (kidx <= qg[r]) && (sk == sq[r]);
                sc[ks][r] = ok ? sc[ks][r] * 0.125f : MASKVAL;
            }
        }
        // row max over 64 keys (local 4 + shfl over 16 lanes)
        float tm[4];
        #pragma unroll
        for (int r = 0; r < 4; ++r)
            tm[r] = fmaxf(fmaxf(sc[0][r], sc[1][r]), fmaxf(sc[2][r], sc[3][r]));
        #pragma unroll
        for (int m = 1; m < 16; m <<= 1)
            #pragma unroll
            for (int r = 0; r < 4; ++r) tm[r] = fmaxf(tm[r], __shfl_xor(tm[r], m));

        float al[4];
        #pragma unroll
        for (int r = 0; r < 4; ++r) {
            float mn = fmaxf(m_[r], tm[r]);
            al[r] = __expf(m_[r] - mn);
            m_[r] = mn;
        }
        // P = exp(s - m), write bf16 to per-wave LDS, accumulate row sums
        float ps[4] = {0.f, 0.f, 0.f, 0.f};
        #pragma unroll
        for (int ks = 0; ks < 4; ++ks) {
            #pragma unroll
            for (int r = 0; r < 4; ++r) {
                float p = __expf(sc[ks][r] - m_[r]);
                ps[r] += p;
                Ps[w][kg * 4 + r][ks * 16 + lc] = f2bf(p);
            }
        }
        #pragma unroll
        for (int m = 1; m < 16; m <<= 1)
            #pragma unroll
            for (int r = 0; r < 4; ++r) ps[r] += __shfl_xor(ps[r], m);
        #pragma unroll
        for (int r = 0; r < 4; ++r) l_[r] = l_[r] * al[r] + ps[r];
        #pragma unroll
        for (int d = 0; d < 4; ++d)
            #pragma unroll
            for (int r = 0; r < 4; ++r) o[d][r] *= al[r];

        __syncthreads();   // P visible before PV; also orders Vs reuse

        // O += P V   (K-dim = 64 keys -> 2 mfma per d sub-tile)
        #pragma unroll
        for (int kf = 0; kf < 2; ++kf) {
            bf16x8 pf = *reinterpret_cast<const bf16x8*>(&Ps[w][lc][kf * 32 + kg * 8]);
            #pragma unroll
            for (int d = 0; d < 4; ++d) {
                u16x8 vt;
                #pragma unroll
                for (int e = 0; e < 8; ++e) vt[e] = Vs[kf * 32 + kg * 8 + e][d * 16 + lc];
                o[d] = mfma16(pf, __builtin_bit_cast(bf16x8, vt), o[d]);
            }
        }
    }

    #pragma unroll
    for (int d = 0; d < 4; ++d)
        #pragma unroll
        for (int r = 0; r < 4; ++r) {
            float v = o[d][r] / fmaxf(l_[r], 1e-20f);
            attn_out[(rowbase + qg[r]) * 1024 + h * 64 + d * 16 + lc] = f2bf(v);
        }
}

// ---------------------------------------------------------------------------
// LayerNorm + residual: out_f = LN(in_bf16)*g + b + res_f32  (g,b,res,out f32)
// WRITE_BF additionally writes bf16 copy (for feeding the next GEMM).
// NOTE: res and out_f may alias (LN2 reads x from d_out, writes final to d_out);
// per-element read-before-write within one thread, so no __restrict__ on them.
// ---------------------------------------------------------------------------
template<bool WRITE_BF>
__global__ __launch_bounds__(256)
void ln_kernel(const u16* __restrict__ in, const float* __restrict__ gam,
               const float* __restrict__ bet, const float* res,
               float* out_f, u16* __restrict__ out_bf)
{
    const int row = blockIdx.x;
    const int tid = threadIdx.x;
    const int lane = tid & 63, w = tid >> 6;
    __shared__ float red1[4], red2[4];

    const size_t base = (size_t)row * 1024 + tid * 4;
    ushort4 xv = *reinterpret_cast<const ushort4*>(in + base);
    float x0 = bf2f(xv.x), x1 = bf2f(xv.y), x2 = bf2f(xv.z), x3 = bf2f(xv.w);

    float s = x0 + x1 + x2 + x3;
    #pragma unroll
    for (int m = 1; m < 64; m <<= 1) s += __shfl_xor(s, m);
    if (lane == 0) red1[w] = s;
    __syncthreads();
    float mu = (red1[0] + red1[1] + red1[2] + red1[3]) * (1.0f / 1024.0f);

    float d0 = x0 - mu, d1 = x1 - mu, d2 = x2 - mu, d3 = x3 - mu;
    float q = d0 * d0 + d1 * d1 + d2 * d2 + d3 * d3;
    #pragma unroll
    for (int m = 1; m < 64; m <<= 1) q += __shfl_xor(q, m);
    if (lane == 0) red2[w] = q;
    __syncthreads();
    float var = (red2[0] + red2[1] + red2[2] + red2[3]) * (1.0f / 1024.0f);
    float rs = rsqrtf(var + 1e-6f);

    float dd[4] = {d0, d1, d2, d3};
    #pragma unroll
    for (int e = 0; e < 4; ++e) {
        int col = tid * 4 + e;
        size_t idx = (size_t)row * 1024 + col;
        float y = dd[e] * rs * gam[col] + bet[col];
        float ov = y + res[idx];
        out_f[idx] = ov;
        if constexpr (WRITE_BF) out_bf[idx] = f2bf(ov);
    }
}

// ---------------------------------------------------------------------------
// Workspace (peak 48 MB). All offsets in bytes; M=1MiB.
//   XB    [0,8M)    x_embeds bf16        (dead after A)
//   KB    [8,14M)   KQV bf16             (dead after A)
//   qkv   [14,38M)  bf16 4096x3072       (dead after B)
//   seg   [38M,+16K)                     (dead after B)
//   attn_o[40,48M)  bf16 4096x1024       (dead after C)
//   WOB   [8,10M)   WO bf16  (after A)   (dead after C)
//   t1    [0,8M)    bf16     (C -> D)
//   x_bf  [8,16M)   bf16     (D -> E)
//   hbuf  [16,48M)  bf16 4096x4096 (E -> F)
//   t2    [0,8M)    bf16     (F -> G)
// d_out (f32, 16MB) doubles as x_f32 between D and G.
// ---------------------------------------------------------------------------
extern "C" void kernel_launch(void* const* d_in, const int* in_sizes, int n_in,
                              void* d_out, int out_size, void* d_ws, size_t ws_size,
                              hipStream_t stream)
{
    const float* x_emb = (const float*)d_in[0];
    const int* tokens  = (const int*)d_in[1];
    const float* KQV   = (const float*)d_in[2];
    const float* WO    = (const float*)d_in[3];
    const float* W_up  = (const float*)d_in[4];
    const float* b_up  = (const float*)d_in[5];
    const float* W_dn  = (const float*)d_in[6];
    const float* b_dn  = (const float*)d_in[7];
    const float* g1    = (const float*)d_in[8];
    const float* be1   = (const float*)d_in[9];
    const float* g2    = (const float*)d_in[10];
    const float* be2   = (const float*)d_in[11];
    const int* start   = (const int*)d_in[12];

    char* ws = (char*)d_ws;
    u16* XB     = (u16*)(ws + 0);
    u16* KB     = (u16*)(ws + 8388608);
    u16* qkv    = (u16*)(ws + 14680064);
    int* seg    = (int*)(ws + 39845888);
    u16* attn_o = (u16*)(ws + 41943040);
    u16* WOB    = (u16*)(ws + 8388608);
    u16* t1     = (u16*)(ws + 0);
    u16* x_bf   = (u16*)(ws + 8388608);
    u16* hbuf   = (u16*)(ws + 16777216);
    u16* t2     = (u16*)(ws + 0);
    float* x_f  = (float*)d_out;
    float* outp = (float*)d_out;

    // converts + seg
    cvt_kernel<<<2048, 256, 0, stream>>>(x_emb, XB);       // 4.19M
    cvt_kernel<<<1536, 256, 0, stream>>>(KQV, KB);         // 3.15M
    seg_kernel<<<2, 256, 0, stream>>>(tokens, start, seg);
    // A. qkv = x_embeds @ KQV
    gemm_kernel<false, false, false><<<dim3(32, 24), 256, 0, stream>>>(XB, KB, nullptr, qkv, 4096, 3072, 1024);
    // WO convert (into dead KB region)
    cvt_kernel<<<512, 256, 0, stream>>>(WO, WOB);          // 1.05M
    // B. attention
    attn_kernel<<<dim3(32, 16, 2), 256, 0, stream>>>(qkv, seg, attn_o);
    // C. t1 = attn_o @ WO
    gemm_kernel<false, false, false><<<dim3(32, 8), 256, 0, stream>>>(attn_o, WOB, nullptr, t1, 4096, 1024, 1024);
    // D. x = LN1(t1) + x_embeds -> x_f (d_out) + x_bf
    ln_kernel<true><<<4096, 256, 0, stream>>>(t1, g1, be1, x_emb, x_f, x_bf);
    // E. h = relu(x @ W_up + b_up)   (B read f32 direct)
    gemm_kernel<true, true, true><<<dim3(32, 32), 256, 0, stream>>>(x_bf, W_up, b_up, hbuf, 4096, 4096, 1024);
    // F. t2 = h @ W_down + b_down    (B read f32 direct)
    gemm_kernel<true, false, true><<<dim3(32, 8), 256, 0, stream>>>(hbuf, W_dn, b_dn, t2, 4096, 1024, 4096);
    // G. out = LN2(t2) + x           (reads+writes d_out)
    ln_kernel<false><<<4096, 256, 0, stream>>>(t2, g2, be2, x_f, outp, nullptr);
}

// Round 4
// 415.744 us; speedup vs baseline: 1.2625x; 1.2625x over previous
//
#include <hip/hip_runtime.h>

typedef unsigned short u16;
typedef unsigned int u32;
typedef __bf16 bf16_t;
typedef bf16_t bf16x8 __attribute__((ext_vector_type(8)));
typedef u16 u16x8 __attribute__((ext_vector_type(8)));
typedef float f32x4 __attribute__((ext_vector_type(4)));

__device__ __forceinline__ float bf2f(u16 u) {
    union { float f; unsigned i; } c; c.i = ((unsigned)u) << 16; return c.f;
}
__device__ __forceinline__ u16 f2bf(float f) {
    union { float f; unsigned i; } c; c.f = f;
    unsigned i = c.i;
    unsigned r = i + 0x7FFFu + ((i >> 16) & 1u);
    return (u16)(r >> 16);
}
__device__ __forceinline__ f32x4 mfma16(bf16x8 a, bf16x8 b, f32x4 c) {
    return __builtin_amdgcn_mfma_f32_16x16x32_bf16(a, b, c, 0, 0, 0);
}

// ---------------------------------------------------------------------------
// f32 -> bf16 conversion, 8 elems/thread, exact grid (n % 2048 == 0)
// ---------------------------------------------------------------------------
__global__ __launch_bounds__(256)
void cvt_kernel(const float* __restrict__ in, u16* __restrict__ out)
{
    const int i = (blockIdx.x * 256 + threadIdx.x) * 8;
    float4 a = *reinterpret_cast<const float4*>(in + i);
    float4 b = *reinterpret_cast<const float4*>(in + i + 4);
    u16x8 o;
    o[0] = f2bf(a.x); o[1] = f2bf(a.y); o[2] = f2bf(a.z); o[3] = f2bf(a.w);
    o[4] = f2bf(b.x); o[5] = f2bf(b.y); o[6] = f2bf(b.z); o[7] = f2bf(b.w);
    *reinterpret_cast<u16x8*>(out + i) = o;
}

// ---------------------------------------------------------------------------
// GEMM: C[M,N] = A[M,K] @ B[K,N]; A,B bf16 row-major; bias f32; C bf16.
// 128x128 tile, BK=32, 4 waves 2x2, each wave 64x64.
// B staged TRANSPOSED into Bt[n][k] (pad 40, XOR k-block by (n>>3)&3) so the
// MFMA B-fragment is a contiguous conflict-floor ds_read_b128.
// ---------------------------------------------------------------------------
template<bool BIAS, bool RELU>
__global__ __launch_bounds__(256)
void gemm_kernel(const u16* __restrict__ A, const u16* __restrict__ B,
                 const float* __restrict__ bias, u16* __restrict__ C,
                 int M, int N, int K)
{
    __shared__ u16 As[128][32];
    __shared__ u16 Bt[128][40];
    const int tid  = threadIdx.x;
    const int lane = tid & 63;
    const int wid  = tid >> 6;
    const int wm = wid >> 1, wn = wid & 1;
    const int bm = blockIdx.x, bn = blockIdx.y;
    const int kg = lane >> 4;   // 0..3
    const int lc = lane & 15;
    const int rp  = tid >> 4;   // 0..15 row-pair for B staging
    const int chb = tid & 15;   // 0..15 col-chunk for B staging

    f32x4 acc[4][4];
    #pragma unroll
    for (int i = 0; i < 4; ++i)
        #pragma unroll
        for (int j = 0; j < 4; ++j)
            acc[i][j] = f32x4{0.f, 0.f, 0.f, 0.f};

    const int nk = K >> 5;
    for (int kt = 0; kt < nk; ++kt) {
        __syncthreads();
        // stage A tile 128x32 (bf16, 512 x 16B chunks)
        #pragma unroll
        for (int p = 0; p < 2; ++p) {
            int c = tid + p * 256;
            int row = c >> 2, ch = c & 3;
            *reinterpret_cast<uint4*>(&As[row][ch * 8]) =
                *reinterpret_cast<const uint4*>(&A[(size_t)(bm * 128 + row) * K + kt * 32 + ch * 8]);
        }
        // stage B tile 32x128 transposed -> Bt[n][k^swz], paired u32 writes
        {
            const u16* bp = &B[(size_t)(kt * 32 + rp * 2) * N + bn * 128 + chb * 8];
            u16x8 va = __builtin_bit_cast(u16x8, *reinterpret_cast<const uint4*>(bp));
            u16x8 vb = __builtin_bit_cast(u16x8, *reinterpret_cast<const uint4*>(bp + N));
            const int kp = (rp * 2) ^ ((chb & 3) << 3);
            #pragma unroll
            for (int j = 0; j < 8; ++j) {
                *reinterpret_cast<u32*>(&Bt[chb * 8 + j][kp]) =
                    (u32)va[j] | ((u32)vb[j] << 16);
            }
        }
        __syncthreads();

        bf16x8 af[4];
        #pragma unroll
        for (int i = 0; i < 4; ++i)
            af[i] = *reinterpret_cast<const bf16x8*>(&As[wm * 64 + i * 16 + lc][kg * 8]);

        #pragma unroll
        for (int j = 0; j < 4; ++j) {
            int col = wn * 64 + j * 16 + lc;
            int kblk = kg ^ ((col >> 3) & 3);
            bf16x8 bfr = *reinterpret_cast<const bf16x8*>(&Bt[col][kblk * 8]);
            #pragma unroll
            for (int i = 0; i < 4; ++i)
                acc[i][j] = mfma16(af[i], bfr, acc[i][j]);
        }
    }

    #pragma unroll
    for (int i = 0; i < 4; ++i) {
        #pragma unroll
        for (int j = 0; j < 4; ++j) {
            int col = bn * 128 + wn * 64 + j * 16 + lc;
            float bv = 0.f;
            if (BIAS) bv = bias[col];
            #pragma unroll
            for (int r = 0; r < 4; ++r) {
                int row = bm * 128 + wm * 64 + i * 16 + kg * 4 + r;
                float v = acc[i][j][r] + bv;
                if (RELU) v = v > 0.f ? v : 0.f;
                C[(size_t)row * N + col] = f2bf(v);
            }
        }
    }
}

// ---------------------------------------------------------------------------
// segment ids: seg[b, s] = inclusive cumsum(tokens == start_id)
// ---------------------------------------------------------------------------
__global__ __launch_bounds__(256)
void seg_kernel(const int* __restrict__ tokens, const int* __restrict__ start_id,
                int* __restrict__ seg)
{
    constexpr int S = 2048;
    __shared__ int part[256];
    __shared__ int pref[256];
    const int b = blockIdx.x, tid = threadIdx.x;
    const int sid = start_id[0];
    const int base = b * S + tid * 8;
    int f[8]; int loc = 0;
    #pragma unroll
    for (int j = 0; j < 8; ++j) { f[j] = (tokens[base + j] == sid) ? 1 : 0; loc += f[j]; }
    part[tid] = loc;
    __syncthreads();
    if (tid == 0) {
        int run = 0;
        for (int i = 0; i < 256; ++i) { pref[i] = run; run += part[i]; }
    }
    __syncthreads();
    int run = pref[tid];
    #pragma unroll
    for (int j = 0; j < 8; ++j) { run += f[j]; seg[base + j] = run; }
}

// ---------------------------------------------------------------------------
// flash attention, causal + segment mask.  grid (S/64, H, B), 256 thr = 4 waves
// K staged row-major padded-72 (b128 reads at conflict floor);
// V staged TRANSPOSED Vt[d][k] with XOR k-block swizzle (paired u32 writes);
// P per-wave in padded LDS. 2 barriers/tile.
// ---------------------------------------------------------------------------
#define MASKVAL -60000.0f
#define MINIT   -30000.0f
__global__ __launch_bounds__(256)
void attn_kernel(const u16* __restrict__ qkv, const int* __restrict__ seg,
                 u16* __restrict__ attn_out)
{
    constexpr int S = 2048, DQ = 3072;
    __shared__ u16 Ks[64][72];
    __shared__ u16 Vt[64][72];
    __shared__ u16 Ps[4][16][72];
    __shared__ int segk[64];

    const int tid = threadIdx.x;
    const int lane = tid & 63, w = tid >> 6;
    const int kg = lane >> 4, lc = lane & 15;
    const int qt = blockIdx.x, h = blockIdx.y, b = blockIdx.z;
    const size_t rowbase = (size_t)b * S;
    const int qbase = qt * 64;
    const int colK = h * 192, colQ = colK + 64, colV = colK + 128;
    const int rpv = tid >> 3;   // 0..31 V row-pair
    const int chv = tid & 7;    // 0..7  V col-chunk

    // Q fragments for this wave's 16 rows (HD=64 -> 2 k-slices)
    bf16x8 qf[2];
    {
        const u16* qp = &qkv[(rowbase + qbase + w * 16 + lc) * DQ + colQ];
        qf[0] = *reinterpret_cast<const bf16x8*>(qp + kg * 8);
        qf[1] = *reinterpret_cast<const bf16x8*>(qp + 32 + kg * 8);
    }
    int qg[4], sq[4];
    float m_[4], l_[4];
    f32x4 o[4];
    #pragma unroll
    for (int r = 0; r < 4; ++r) {
        qg[r] = qbase + w * 16 + kg * 4 + r;
        sq[r] = seg[rowbase + qg[r]];
        m_[r] = MINIT; l_[r] = 0.f;
    }
    #pragma unroll
    for (int d = 0; d < 4; ++d) o[d] = f32x4{0.f, 0.f, 0.f, 0.f};

    for (int kb = 0; kb <= qt; ++kb) {
        __syncthreads();
        // K rows (2 passes of 256 x 16B)
        #pragma unroll
        for (int p = 0; p < 2; ++p) {
            int c = tid + p * 256;
            int row = c >> 3, ch = c & 7;
            const size_t gr = (rowbase + (size_t)kb * 64 + row) * DQ;
            *reinterpret_cast<uint4*>(&Ks[row][ch * 8]) =
                *reinterpret_cast<const uint4*>(&qkv[gr + colK + ch * 8]);
        }
        // V transposed: thread loads rows 2rpv,2rpv+1 cols chv*8..+8, writes u32 pairs
        {
            const size_t gr = (rowbase + (size_t)kb * 64 + rpv * 2) * DQ + colV + chv * 8;
            u16x8 va = __builtin_bit_cast(u16x8, *reinterpret_cast<const uint4*>(&qkv[gr]));
            u16x8 vb = __builtin_bit_cast(u16x8, *reinterpret_cast<const uint4*>(&qkv[gr + DQ]));
            const int kp = (rpv * 2) ^ ((chv & 3) << 3);
            #pragma unroll
            for (int j = 0; j < 8; ++j) {
                *reinterpret_cast<u32*>(&Vt[chv * 8 + j][kp]) =
                    (u32)va[j] | ((u32)vb[j] << 16);
            }
        }
        if (tid < 64) segk[tid] = seg[rowbase + kb * 64 + tid];
        __syncthreads();

        // S = Q K^T  (4 key sub-tiles of 16)
        f32x4 sc[4];
        #pragma unroll
        for (int ks = 0; ks < 4; ++ks) {
            bf16x8 kf0 = *reinterpret_cast<const bf16x8*>(&Ks[ks * 16 + lc][kg * 8]);
            bf16x8 kf1 = *reinterpret_cast<const bf16x8*>(&Ks[ks * 16 + lc][32 + kg * 8]);
            f32x4 s = f32x4{0.f, 0.f, 0.f, 0.f};
            s = mfma16(qf[0], kf0, s);
            s = mfma16(qf[1], kf1, s);
            sc[ks] = s;
        }
        // mask + scale (1/sqrt(64) = 0.125)
        #pragma unroll
        for (int ks = 0; ks < 4; ++ks) {
            int kidx = kb * 64 + ks * 16 + lc;
            int sk = segk[ks * 16 + lc];
            #pragma unroll
            for (int r = 0; r < 4; ++r) {
                bool ok = (kidx <= qg[r]) && (sk == sq[r]);
                sc[ks][r] = ok ? sc[ks][r] * 0.125f : MASKVAL;
            }
        }
        // row max over 64 keys (local 4 + shfl over 16 lanes)
        float tm[4];
        #pragma unroll
        for (int r = 0; r < 4; ++r)
            tm[r] = fmaxf(fmaxf(sc[0][r], sc[1][r]), fmaxf(sc[2][r], sc[3][r]));
        #pragma unroll
        for (int m = 1; m < 16; m <<= 1)
            #pragma unroll
            for (int r = 0; r < 4; ++r) tm[r] = fmaxf(tm[r], __shfl_xor(tm[r], m));

        float al[4];
        #pragma unroll
        for (int r = 0; r < 4; ++r) {
            float mn = fmaxf(m_[r], tm[r]);
            al[r] = __expf(m_[r] - mn);
            m_[r] = mn;
        }
        // P = exp(s - m), bf16 to per-wave LDS; row sums
        float ps[4] = {0.f, 0.f, 0.f, 0.f};
        #pragma unroll
        for (int ks = 0; ks < 4; ++ks) {
            #pragma unroll
            for (int r = 0; r < 4; ++r) {
                float p = __expf(sc[ks][r] - m_[r]);
                ps[r] += p;
                Ps[w][kg * 4 + r][ks * 16 + lc] = f2bf(p);
            }
        }
        #pragma unroll
        for (int m = 1; m < 16; m <<= 1)
            #pragma unroll
            for (int r = 0; r < 4; ++r) ps[r] += __shfl_xor(ps[r], m);
        #pragma unroll
        for (int r = 0; r < 4; ++r) l_[r] = l_[r] * al[r] + ps[r];
        #pragma unroll
        for (int d = 0; d < 4; ++d)
            #pragma unroll
            for (int r = 0; r < 4; ++r) o[d][r] *= al[r];

        // O += P V : P per-wave (same-wave LDS RAW, compiler-ordered); V from Vt
        #pragma unroll
        for (int kf = 0; kf < 2; ++kf) {
            bf16x8 pf = *reinterpret_cast<const bf16x8*>(&Ps[w][lc][kf * 32 + kg * 8]);
            #pragma unroll
            for (int d = 0; d < 4; ++d) {
                int vrow = d * 16 + lc;
                int kblk = kg ^ ((vrow >> 3) & 3);
                bf16x8 vf = *reinterpret_cast<const bf16x8*>(&Vt[vrow][kf * 32 + kblk * 8]);
                o[d] = mfma16(pf, vf, o[d]);
            }
        }
    }

    #pragma unroll
    for (int d = 0; d < 4; ++d)
        #pragma unroll
        for (int r = 0; r < 4; ++r) {
            float v = o[d][r] / fmaxf(l_[r], 1e-20f);
            attn_out[(rowbase + qg[r]) * 1024 + h * 64 + d * 16 + lc] = f2bf(v);
        }
}

// ---------------------------------------------------------------------------
// LayerNorm + residual: out_f = LN(in_bf16)*g + b + res_f32  (g,b,res,out f32)
// WRITE_BF additionally writes bf16 copy (for feeding the next GEMM).
// res/out_f may alias (per-element read-before-write in one thread).
// ---------------------------------------------------------------------------
template<bool WRITE_BF>
__global__ __launch_bounds__(256)
void ln_kernel(const u16* __restrict__ in, const float* __restrict__ gam,
               const float* __restrict__ bet, const float* res,
               float* out_f, u16* __restrict__ out_bf)
{
    const int row = blockIdx.x;
    const int tid = threadIdx.x;
    const int lane = tid & 63, w = tid >> 6;
    __shared__ float red1[4], red2[4];

    const size_t base = (size_t)row * 1024 + tid * 4;
    ushort4 xv = *reinterpret_cast<const ushort4*>(in + base);
    float x0 = bf2f(xv.x), x1 = bf2f(xv.y), x2 = bf2f(xv.z), x3 = bf2f(xv.w);

    float s = x0 + x1 + x2 + x3;
    #pragma unroll
    for (int m = 1; m < 64; m <<= 1) s += __shfl_xor(s, m);
    if (lane == 0) red1[w] = s;
    __syncthreads();
    float mu = (red1[0] + red1[1] + red1[2] + red1[3]) * (1.0f / 1024.0f);

    float d0 = x0 - mu, d1 = x1 - mu, d2 = x2 - mu, d3 = x3 - mu;
    float q = d0 * d0 + d1 * d1 + d2 * d2 + d3 * d3;
    #pragma unroll
    for (int m = 1; m < 64; m <<= 1) q += __shfl_xor(q, m);
    if (lane == 0) red2[w] = q;
    __syncthreads();
    float var = (red2[0] + red2[1] + red2[2] + red2[3]) * (1.0f / 1024.0f);
    float rs = rsqrtf(var + 1e-6f);

    float dd[4] = {d0, d1, d2, d3};
    #pragma unroll
    for (int e = 0; e < 4; ++e) {
        int col = tid * 4 + e;
        size_t idx = (size_t)row * 1024 + col;
        float y = dd[e] * rs * gam[col] + bet[col];
        float ov = y + res[idx];
        out_f[idx] = ov;
        if constexpr (WRITE_BF) out_bf[idx] = f2bf(ov);
    }
}

// ---------------------------------------------------------------------------
// Workspace (peak 48 MB). Offsets in bytes.
//   XB    [0,8M)    x_emb bf16   (A)        -> t1 (C-D) -> WUB (E) -> WDB (F)
//   KB    [8,14M)   KQV bf16     (A)        -> WOB [8,10M) (C) -> x_bf (D-E) -> t2 (F-G)
//   qkv   [14,38M)  bf16 4096x3072 (A-B)
//   seg   [38M]     16KB          (A-B)
//   attn_o[40,48M)  bf16 (B-C)
//   hbuf  [16,48M)  bf16 4096x4096 (E-F)
// d_out (f32 16MB) holds x (residual) from D to G.
// ---------------------------------------------------------------------------
extern "C" void kernel_launch(void* const* d_in, const int* in_sizes, int n_in,
                              void* d_out, int out_size, void* d_ws, size_t ws_size,
                              hipStream_t stream)
{
    const float* x_emb = (const float*)d_in[0];
    const int* tokens  = (const int*)d_in[1];
    const float* KQV   = (const float*)d_in[2];
    const float* WO    = (const float*)d_in[3];
    const float* W_up  = (const float*)d_in[4];
    const float* b_up  = (const float*)d_in[5];
    const float* W_dn  = (const float*)d_in[6];
    const float* b_dn  = (const float*)d_in[7];
    const float* g1    = (const float*)d_in[8];
    const float* be1   = (const float*)d_in[9];
    const float* g2    = (const float*)d_in[10];
    const float* be2   = (const float*)d_in[11];
    const int* start   = (const int*)d_in[12];

    char* ws = (char*)d_ws;
    u16* XB     = (u16*)(ws + 0);
    u16* KB     = (u16*)(ws + 8388608);
    u16* qkv    = (u16*)(ws + 14680064);
    int* seg    = (int*)(ws + 39845888);
    u16* attn_o = (u16*)(ws + 41943040);
    u16* WOB    = (u16*)(ws + 8388608);
    u16* t1     = (u16*)(ws + 0);
    u16* x_bf   = (u16*)(ws + 8388608);
    u16* WUB    = (u16*)(ws + 0);
    u16* hbuf   = (u16*)(ws + 16777216);
    u16* WDB    = (u16*)(ws + 0);
    u16* t2     = (u16*)(ws + 8388608);
    float* x_f  = (float*)d_out;
    float* outp = (float*)d_out;

    // converts + seg
    cvt_kernel<<<2048, 256, 0, stream>>>(x_emb, XB);
    cvt_kernel<<<1536, 256, 0, stream>>>(KQV, KB);
    seg_kernel<<<2, 256, 0, stream>>>(tokens, start, seg);
    // A. qkv = x_embeds @ KQV
    gemm_kernel<false, false><<<dim3(32, 24), 256, 0, stream>>>(XB, KB, nullptr, qkv, 4096, 3072, 1024);
    // WO convert (into dead KB region)
    cvt_kernel<<<512, 256, 0, stream>>>(WO, WOB);
    // B. attention
    attn_kernel<<<dim3(32, 16, 2), 256, 0, stream>>>(qkv, seg, attn_o);
    // C. t1 = attn_o @ WO  (t1 overwrites dead XB)
    gemm_kernel<false, false><<<dim3(32, 8), 256, 0, stream>>>(attn_o, WOB, nullptr, t1, 4096, 1024, 1024);
    // D. x = LN1(t1) + x_embeds -> x_f (d_out) + x_bf
    ln_kernel<true><<<4096, 256, 0, stream>>>(t1, g1, be1, x_emb, x_f, x_bf);
    // W_up convert (t1 dead)
    cvt_kernel<<<2048, 256, 0, stream>>>(W_up, WUB);
    // E. h = relu(x @ W_up + b_up)
    gemm_kernel<true, true><<<dim3(32, 32), 256, 0, stream>>>(x_bf, WUB, b_up, hbuf, 4096, 4096, 1024);
    // W_down convert (WUB dead)
    cvt_kernel<<<2048, 256, 0, stream>>>(W_dn, WDB);
    // F. t2 = h @ W_down + b_down  (t2 overwrites dead x_bf)
    gemm_kernel<true, false><<<dim3(32, 8), 256, 0, stream>>>(hbuf, WDB, b_dn, t2, 4096, 1024, 4096);
    // G. out = LN2(t2) + x   (reads+writes d_out)
    ln_kernel<false><<<4096, 256, 0, stream>>>(t2, g2, be2, x_f, outp, nullptr);
}

// Round 5
// 325.454 us; speedup vs baseline: 1.6127x; 1.2774x over previous
//
#include <hip/hip_runtime.h>

typedef unsigned short u16;
typedef unsigned int u32;
typedef __bf16 bf16_t;
typedef bf16_t bf16x8 __attribute__((ext_vector_type(8)));
typedef u16 u16x8 __attribute__((ext_vector_type(8)));
typedef float f32x4 __attribute__((ext_vector_type(4)));

__device__ __forceinline__ float bf2f(u16 u) {
    union { float f; unsigned i; } c; c.i = ((unsigned)u) << 16; return c.f;
}
__device__ __forceinline__ u16 f2bf(float f) {
    union { float f; unsigned i; } c; c.f = f;
    unsigned i = c.i;
    unsigned r = i + 0x7FFFu + ((i >> 16) & 1u);
    return (u16)(r >> 16);
}
__device__ __forceinline__ f32x4 mfma16(bf16x8 a, bf16x8 b, f32x4 c) {
    return __builtin_amdgcn_mfma_f32_16x16x32_bf16(a, b, c, 0, 0, 0);
}
// async global->LDS, 16B per lane; LDS dest must be linear in lane
__device__ __forceinline__ void gld16(const u16* g, u16* l) {
    __builtin_amdgcn_global_load_lds(
        (const __attribute__((address_space(1))) void*)g,
        (__attribute__((address_space(3))) void*)l, 16, 0, 0);
}

// ---------------------------------------------------------------------------
// f32 -> bf16, 8 elems/thread
// ---------------------------------------------------------------------------
__global__ __launch_bounds__(256)
void cvt_kernel(const float* __restrict__ in, u16* __restrict__ out)
{
    const int i = (blockIdx.x * 256 + threadIdx.x) * 8;
    float4 a = *reinterpret_cast<const float4*>(in + i);
    float4 b = *reinterpret_cast<const float4*>(in + i + 4);
    u16x8 o;
    o[0] = f2bf(a.x); o[1] = f2bf(a.y); o[2] = f2bf(a.z); o[3] = f2bf(a.w);
    o[4] = f2bf(b.x); o[5] = f2bf(b.y); o[6] = f2bf(b.z); o[7] = f2bf(b.w);
    *reinterpret_cast<u16x8*>(out + i) = o;
}

// ---------------------------------------------------------------------------
// f32 [K][N] -> bf16 transposed [N][K].  grid (K/32, N/32), 256 thr.
// ---------------------------------------------------------------------------
__global__ __launch_bounds__(256)
void cvt_t_kernel(const float* __restrict__ in, u16* __restrict__ out,
                  int K, int N)
{
    __shared__ float tile[32][33];
    const int kb = blockIdx.x * 32, nb = blockIdx.y * 32;
    const int r = threadIdx.x >> 3, c4 = threadIdx.x & 7;
    float4 v = *reinterpret_cast<const float4*>(&in[(size_t)(kb + r) * N + nb + c4 * 4]);
    tile[r][c4 * 4 + 0] = v.x; tile[r][c4 * 4 + 1] = v.y;
    tile[r][c4 * 4 + 2] = v.z; tile[r][c4 * 4 + 3] = v.w;
    __syncthreads();
    ushort4 o;
    o.x = f2bf(tile[c4 * 4 + 0][r]);
    o.y = f2bf(tile[c4 * 4 + 1][r]);
    o.z = f2bf(tile[c4 * 4 + 2][r]);
    o.w = f2bf(tile[c4 * 4 + 3][r]);
    *reinterpret_cast<ushort4*>(&out[(size_t)(nb + r) * K + kb + c4 * 4]) = o;
}

// ---------------------------------------------------------------------------
// GEMM: C[M,N] = A[M,K] @ B[K,N] with B PRE-TRANSPOSED (Bt[N][K]).
// BM x 128 tile, BK=32, 4 waves.  Both tiles staged via global_load_lds(16B)
// into linear LDS; frag-read conflicts halved by pre-swizzled global chunk
// (kc ^= row&3), same XOR applied on read.
// ---------------------------------------------------------------------------
template<int BM, bool BIAS, bool RELU>
__global__ __launch_bounds__(256)
void gemm_kernel(const u16* __restrict__ A, const u16* __restrict__ Bt,
                 const float* __restrict__ bias, u16* __restrict__ C,
                 int M, int N, int K)
{
    __shared__ u16 As[BM][32];
    __shared__ u16 Bs[128][32];
    constexpr int AI = BM / 32;       // 4 (BM=128) or 2 (BM=64)
    const int tid  = threadIdx.x;
    const int lane = tid & 63;
    const int wid  = tid >> 6;
    const int wm = wid >> 1, wn = wid & 1;
    const int bm = blockIdx.x, bn = blockIdx.y;
    const int kg = lane >> 4;
    const int lc = lane & 15;
    const int pk = kg ^ (lc & 3);     // swizzled k-chunk for frag reads

    f32x4 acc[AI][4];
    #pragma unroll
    for (int i = 0; i < AI; ++i)
        #pragma unroll
        for (int j = 0; j < 4; ++j)
            acc[i][j] = f32x4{0.f, 0.f, 0.f, 0.f};

    const int nk = K >> 5;
    for (int kt = 0; kt < nk; ++kt) {
        __syncthreads();
        // A tile: BM*4 chunks of 16B; chunk c -> LDS slot c, global kc = (c&3)^(row&3)
        #pragma unroll
        for (int p = 0; p < BM / 64; ++p) {
            int c = wid * BM + p * 64 + lane;
            int row = c >> 2;
            int ko = ((c & 3) ^ (row & 3)) * 8;
            gld16(A + (size_t)(bm * BM + row) * K + kt * 32 + ko,
                  &As[0][0] + c * 8);
        }
        // B tile: 512 chunks
        #pragma unroll
        for (int p = 0; p < 2; ++p) {
            int c = wid * 128 + p * 64 + lane;
            int row = c >> 2;
            int ko = ((c & 3) ^ (row & 3)) * 8;
            gld16(Bt + (size_t)(bn * 128 + row) * K + kt * 32 + ko,
                  &Bs[0][0] + c * 8);
        }
        __syncthreads();

        bf16x8 af[AI], bf[4];
        #pragma unroll
        for (int i = 0; i < AI; ++i)
            af[i] = *reinterpret_cast<const bf16x8*>(&As[wm * (BM / 2) + i * 16 + lc][pk * 8]);
        #pragma unroll
        for (int j = 0; j < 4; ++j)
            bf[j] = *reinterpret_cast<const bf16x8*>(&Bs[wn * 64 + j * 16 + lc][pk * 8]);

        #pragma unroll
        for (int j = 0; j < 4; ++j)
            #pragma unroll
            for (int i = 0; i < AI; ++i)
                acc[i][j] = mfma16(af[i], bf[j], acc[i][j]);
    }

    #pragma unroll
    for (int i = 0; i < AI; ++i) {
        #pragma unroll
        for (int j = 0; j < 4; ++j) {
            int col = bn * 128 + wn * 64 + j * 16 + lc;
            float bv = 0.f;
            if (BIAS) bv = bias[col];
            #pragma unroll
            for (int r = 0; r < 4; ++r) {
                int row = bm * BM + wm * (BM / 2) + i * 16 + kg * 4 + r;
                float v = acc[i][j][r] + bv;
                if (RELU) v = v > 0.f ? v : 0.f;
                C[(size_t)row * N + col] = f2bf(v);
            }
        }
    }
}

// ---------------------------------------------------------------------------
// segment ids
// ---------------------------------------------------------------------------
__global__ __launch_bounds__(256)
void seg_kernel(const int* __restrict__ tokens, const int* __restrict__ start_id,
                int* __restrict__ seg)
{
    constexpr int S = 2048;
    __shared__ int part[256];
    __shared__ int pref[256];
    const int b = blockIdx.x, tid = threadIdx.x;
    const int sid = start_id[0];
    const int base = b * S + tid * 8;
    int f[8]; int loc = 0;
    #pragma unroll
    for (int j = 0; j < 8; ++j) { f[j] = (tokens[base + j] == sid) ? 1 : 0; loc += f[j]; }
    part[tid] = loc;
    __syncthreads();
    if (tid == 0) {
        int run = 0;
        for (int i = 0; i < 256; ++i) { pref[i] = run; run += part[i]; }
    }
    __syncthreads();
    int run = pref[tid];
    #pragma unroll
    for (int j = 0; j < 8; ++j) { run += f[j]; seg[base + j] = run; }
}

// ---------------------------------------------------------------------------
// flash attention, causal + segment mask, paired q-tiles for load balance.
// grid (16 pairs, H, B), 512 thr = 8 waves: waves 0-3 -> q-tile pr,
// waves 4-7 -> q-tile 31-pr (uniform 33 wave-tiles/block).
// Swapped QK^T: sT = mfma(K, Q) so each lane owns ONE q row (q = lc);
// P written as b64 vectors to Pt[q][k], read back as b128 PV A-fragments.
// ---------------------------------------------------------------------------
#define MASKVAL -60000.0f
#define MINIT   -30000.0f
__global__ __launch_bounds__(512)
void attn_kernel(const u16* __restrict__ qkv, const int* __restrict__ seg,
                 u16* __restrict__ attn_out)
{
    constexpr int S = 2048, DQ = 3072;
    __shared__ u16 Ks[64][72];
    __shared__ u16 Vt[64][72];
    __shared__ u16 Pt[8][16][72];
    __shared__ int segk[64];

    const int tid = threadIdx.x;
    const int lane = tid & 63, w = tid >> 6;
    const int kg = lane >> 4, lc = lane & 15;
    const int pr = blockIdx.x, h = blockIdx.y, b = blockIdx.z;
    const int qt = (w < 4) ? pr : (31 - pr);
    const int nkb = 31 - pr;                 // shared kb range (max of pair)
    const size_t rowbase = (size_t)b * S;
    const int colK = h * 192, colQ = colK + 64, colV = colK + 128;
    const int qrow = qt * 64 + (w & 3) * 16 + lc;   // this lane's q row

    bf16x8 qf0, qf1;
    {
        const u16* qp = &qkv[(rowbase + qrow) * DQ + colQ];
        qf0 = *reinterpret_cast<const bf16x8*>(qp + kg * 8);
        qf1 = *reinterpret_cast<const bf16x8*>(qp + 32 + kg * 8);
    }
    const int sq = seg[rowbase + qrow];
    float m_ = MINIT, l_ = 0.f;
    f32x4 o[4];
    #pragma unroll
    for (int d = 0; d < 4; ++d) o[d] = f32x4{0.f, 0.f, 0.f, 0.f};

    for (int kb = 0; kb <= nkb; ++kb) {
        __syncthreads();
        if (tid < 256) {
            // V transposed with XOR k-block swizzle (paired u32 writes)
            const int rpv = tid >> 3, chv = tid & 7;
            const size_t gr = (rowbase + (size_t)kb * 64 + rpv * 2) * DQ + colV + chv * 8;
            u16x8 va = __builtin_bit_cast(u16x8, *reinterpret_cast<const uint4*>(&qkv[gr]));
            u16x8 vb = __builtin_bit_cast(u16x8, *reinterpret_cast<const uint4*>(&qkv[gr + DQ]));
            const int kp = (rpv * 2) ^ ((chv & 3) << 3);
            #pragma unroll
            for (int j = 0; j < 8; ++j)
                *reinterpret_cast<u32*>(&Vt[chv * 8 + j][kp]) =
                    (u32)va[j] | ((u32)vb[j] << 16);
            if (tid < 64) segk[tid] = seg[rowbase + kb * 64 + tid];
        } else {
            // K rows, 2 chunks per thread
            const int t = tid - 256;
            #pragma unroll
            for (int p = 0; p < 2; ++p) {
                int c = t + p * 256;
                int row = c >> 3, ch = c & 7;
                *reinterpret_cast<uint4*>(&Ks[row][ch * 8]) =
                    *reinterpret_cast<const uint4*>(
                        &qkv[(rowbase + (size_t)kb * 64 + row) * DQ + colK + ch * 8]);
            }
        }
        __syncthreads();

        if (kb <= qt) {
            // S^T = mfma(K, Q): lane holds S[q=qrow][k = kb*64 + ks*16 + kg*4 + r]
            f32x4 sT[4];
            #pragma unroll
            for (int ks = 0; ks < 4; ++ks) {
                bf16x8 kf0 = *reinterpret_cast<const bf16x8*>(&Ks[ks * 16 + lc][kg * 8]);
                bf16x8 kf1 = *reinterpret_cast<const bf16x8*>(&Ks[ks * 16 + lc][32 + kg * 8]);
                f32x4 s = f32x4{0.f, 0.f, 0.f, 0.f};
                s = mfma16(kf0, qf0, s);
                s = mfma16(kf1, qf1, s);
                sT[ks] = s;
            }
            // mask + scale
            #pragma unroll
            for (int ks = 0; ks < 4; ++ks) {
                #pragma unroll
                for (int r = 0; r < 4; ++r) {
                    int kk = ks * 16 + kg * 4 + r;
                    bool ok = (kb * 64 + kk <= qrow) && (segk[kk] == sq);
                    sT[ks][r] = ok ? sT[ks][r] * 0.125f : MASKVAL;
                }
            }
            // row max (16 local + 2 shfl over kg groups)
            float tm = fmaxf(fmaxf(fmaxf(sT[0][0], sT[0][1]), fmaxf(sT[0][2], sT[0][3])),
                             fmaxf(fmaxf(sT[1][0], sT[1][1]), fmaxf(sT[1][2], sT[1][3])));
            tm = fmaxf(tm, fmaxf(fmaxf(fmaxf(sT[2][0], sT[2][1]), fmaxf(sT[2][2], sT[2][3])),
                                 fmaxf(fmaxf(sT[3][0], sT[3][1]), fmaxf(sT[3][2], sT[3][3]))));
            tm = fmaxf(tm, __shfl_xor(tm, 16));
            tm = fmaxf(tm, __shfl_xor(tm, 32));
            float mn = fmaxf(m_, tm);
            float al = __expf(m_ - mn);
            m_ = mn;
            // P = exp(s-m) -> Pt[w][q][k] as b64 writes; accumulate row sum
            float ps = 0.f;
            #pragma unroll
            for (int ks = 0; ks < 4; ++ks) {
                ushort4 pw;
                float p0 = __expf(sT[ks][0] - m_); ps += p0; pw.x = f2bf(p0);
                float p1 = __expf(sT[ks][1] - m_); ps += p1; pw.y = f2bf(p1);
                float p2 = __expf(sT[ks][2] - m_); ps += p2; pw.z = f2bf(p2);
                float p3 = __expf(sT[ks][3] - m_); ps += p3; pw.w = f2bf(p3);
                *reinterpret_cast<ushort4*>(&Pt[w][lc][ks * 16 + kg * 4]) = pw;
            }
            ps += __shfl_xor(ps, 16);
            ps += __shfl_xor(ps, 32);
            l_ = l_ * al + ps;
            // rescale O (q = kg*4+r on accumulator side -> broadcast al)
            float alr[4];
            #pragma unroll
            for (int r = 0; r < 4; ++r) alr[r] = __shfl(al, kg * 4 + r);
            #pragma unroll
            for (int d = 0; d < 4; ++d)
                #pragma unroll
                for (int r = 0; r < 4; ++r) o[d][r] *= alr[r];
            // O += P V  (P per-wave, same-wave RAW ordered by compiler)
            #pragma unroll
            for (int kf = 0; kf < 2; ++kf) {
                bf16x8 pf = *reinterpret_cast<const bf16x8*>(&Pt[w][lc][kf * 32 + kg * 8]);
                #pragma unroll
                for (int d = 0; d < 4; ++d) {
                    int vrow = d * 16 + lc;
                    int kblk = kg ^ ((vrow >> 3) & 3);
                    bf16x8 vf = *reinterpret_cast<const bf16x8*>(&Vt[vrow][kf * 32 + kblk * 8]);
                    o[d] = mfma16(pf, vf, o[d]);
                }
            }
        }
    }

    float lr[4];
    #pragma unroll
    for (int r = 0; r < 4; ++r) lr[r] = __shfl(l_, kg * 4 + r);
    #pragma unroll
    for (int d = 0; d < 4; ++d)
        #pragma unroll
        for (int r = 0; r < 4; ++r) {
            float v = o[d][r] / fmaxf(lr[r], 1e-20f);
            int qo = qt * 64 + (w & 3) * 16 + kg * 4 + r;
            attn_out[(rowbase + qo) * 1024 + h * 64 + d * 16 + lc] = f2bf(v);
        }
}

// ---------------------------------------------------------------------------
// LayerNorm + residual: out_f = LN(in_bf16)*g + b + res_f32
// ---------------------------------------------------------------------------
template<bool WRITE_BF>
__global__ __launch_bounds__(256)
void ln_kernel(const u16* __restrict__ in, const float* __restrict__ gam,
               const float* __restrict__ bet, const float* res,
               float* out_f, u16* __restrict__ out_bf)
{
    const int row = blockIdx.x;
    const int tid = threadIdx.x;
    const int lane = tid & 63, w = tid >> 6;
    __shared__ float red1[4], red2[4];

    const size_t base = (size_t)row * 1024 + tid * 4;
    ushort4 xv = *reinterpret_cast<const ushort4*>(in + base);
    float x0 = bf2f(xv.x), x1 = bf2f(xv.y), x2 = bf2f(xv.z), x3 = bf2f(xv.w);

    float s = x0 + x1 + x2 + x3;
    #pragma unroll
    for (int m = 1; m < 64; m <<= 1) s += __shfl_xor(s, m);
    if (lane == 0) red1[w] = s;
    __syncthreads();
    float mu = (red1[0] + red1[1] + red1[2] + red1[3]) * (1.0f / 1024.0f);

    float d0 = x0 - mu, d1 = x1 - mu, d2 = x2 - mu, d3 = x3 - mu;
    float q = d0 * d0 + d1 * d1 + d2 * d2 + d3 * d3;
    #pragma unroll
    for (int m = 1; m < 64; m <<= 1) q += __shfl_xor(q, m);
    if (lane == 0) red2[w] = q;
    __syncthreads();
    float var = (red2[0] + red2[1] + red2[2] + red2[3]) * (1.0f / 1024.0f);
    float rs = rsqrtf(var + 1e-6f);

    float dd[4] = {d0, d1, d2, d3};
    #pragma unroll
    for (int e = 0; e < 4; ++e) {
        int col = tid * 4 + e;
        size_t idx = (size_t)row * 1024 + col;
        float y = dd[e] * rs * gam[col] + bet[col];
        float ov = y + res[idx];
        out_f[idx] = ov;
        if constexpr (WRITE_BF) out_bf[idx] = f2bf(ov);
    }
}

// ---------------------------------------------------------------------------
// Workspace (peak 48 MB), weights stored TRANSPOSED (bf16 [N][K]):
//   XB    [0,8M)  x_emb bf16 (A)  -> t1 (C-D) -> WUBt (E) -> WDBt (F)
//   KBt   [8,14M) KQV^T (A)       -> WOBt [8,10M) (C) -> x_bf (D-E) -> t2 (F-G)
//   qkv   [14,38M), seg [38M], attn_o [40,48M), hbuf [16,48M) (E-F)
// d_out (f32 16MB) holds residual x from D to G.
// ---------------------------------------------------------------------------
extern "C" void kernel_launch(void* const* d_in, const int* in_sizes, int n_in,
                              void* d_out, int out_size, void* d_ws, size_t ws_size,
                              hipStream_t stream)
{
    const float* x_emb = (const float*)d_in[0];
    const int* tokens  = (const int*)d_in[1];
    const float* KQV   = (const float*)d_in[2];
    const float* WO    = (const float*)d_in[3];
    const float* W_up  = (const float*)d_in[4];
    const float* b_up  = (const float*)d_in[5];
    const float* W_dn  = (const float*)d_in[6];
    const float* b_dn  = (const float*)d_in[7];
    const float* g1    = (const float*)d_in[8];
    const float* be1   = (const float*)d_in[9];
    const float* g2    = (const float*)d_in[10];
    const float* be2   = (const float*)d_in[11];
    const int* start   = (const int*)d_in[12];

    char* ws = (char*)d_ws;
    u16* XB     = (u16*)(ws + 0);
    u16* KBt    = (u16*)(ws + 8388608);
    u16* qkv    = (u16*)(ws + 14680064);
    int* seg    = (int*)(ws + 39845888);
    u16* attn_o = (u16*)(ws + 41943040);
    u16* WOBt   = (u16*)(ws + 8388608);
    u16* t1     = (u16*)(ws + 0);
    u16* x_bf   = (u16*)(ws + 8388608);
    u16* WUBt   = (u16*)(ws + 0);
    u16* hbuf   = (u16*)(ws + 16777216);
    u16* WDBt   = (u16*)(ws + 0);
    u16* t2     = (u16*)(ws + 8388608);
    float* x_f  = (float*)d_out;
    float* outp = (float*)d_out;

    cvt_kernel<<<2048, 256, 0, stream>>>(x_emb, XB);
    cvt_t_kernel<<<dim3(32, 96), 256, 0, stream>>>(KQV, KBt, 1024, 3072);
    seg_kernel<<<2, 256, 0, stream>>>(tokens, start, seg);
    // A. qkv = x_embeds @ KQV
    gemm_kernel<128, false, false><<<dim3(32, 24), 256, 0, stream>>>(XB, KBt, nullptr, qkv, 4096, 3072, 1024);
    cvt_t_kernel<<<dim3(32, 32), 256, 0, stream>>>(WO, WOBt, 1024, 1024);
    // B. attention (paired q-tiles)
    attn_kernel<<<dim3(16, 16, 2), 512, 0, stream>>>(qkv, seg, attn_o);
    // C. t1 = attn_o @ WO
    gemm_kernel<64, false, false><<<dim3(64, 8), 256, 0, stream>>>(attn_o, WOBt, nullptr, t1, 4096, 1024, 1024);
    // D. x = LN1(t1) + x_embeds
    ln_kernel<true><<<4096, 256, 0, stream>>>(t1, g1, be1, x_emb, x_f, x_bf);
    cvt_t_kernel<<<dim3(32, 128), 256, 0, stream>>>(W_up, WUBt, 1024, 4096);
    // E. h = relu(x @ W_up + b_up)
    gemm_kernel<128, true, true><<<dim3(32, 32), 256, 0, stream>>>(x_bf, WUBt, b_up, hbuf, 4096, 4096, 1024);
    cvt_t_kernel<<<dim3(128, 32), 256, 0, stream>>>(W_dn, WDBt, 4096, 1024);
    // F. t2 = h @ W_down + b_down
    gemm_kernel<64, true, false><<<dim3(64, 8), 256, 0, stream>>>(hbuf, WDBt, b_dn, t2, 4096, 1024, 4096);
    // G. out = LN2(t2) + x
    ln_kernel<false><<<4096, 256, 0, stream>>>(t2, g2, be2, x_f, outp, nullptr);
}

// Round 6
// 252.018 us; speedup vs baseline: 2.0826x; 1.2914x over previous
//
#include <hip/hip_runtime.h>

typedef unsigned short u16;
typedef unsigned int u32;
typedef __bf16 bf16_t;
typedef bf16_t bf16x8 __attribute__((ext_vector_type(8)));
typedef u16 u16x8 __attribute__((ext_vector_type(8)));
typedef float f32x4 __attribute__((ext_vector_type(4)));

__device__ __forceinline__ float bf2f(u16 u) {
    union { float f; unsigned i; } c; c.i = ((unsigned)u) << 16; return c.f;
}
__device__ __forceinline__ u16 f2bf(float f) {
    return __builtin_bit_cast(u16, (bf16_t)f);   // native v_cvt (RTNE on gfx950)
}
__device__ __forceinline__ f32x4 mfma16(bf16x8 a, bf16x8 b, f32x4 c) {
    return __builtin_amdgcn_mfma_f32_16x16x32_bf16(a, b, c, 0, 0, 0);
}
__device__ __forceinline__ void gld16(const u16* g, u16* l) {
    __builtin_amdgcn_global_load_lds(
        (const __attribute__((address_space(1))) void*)g,
        (__attribute__((address_space(3))) void*)l, 16, 0, 0);
}

// ---------------------------------------------------------------------------
// f32 -> bf16, 8 elems/thread
// ---------------------------------------------------------------------------
__global__ __launch_bounds__(256)
void cvt_kernel(const float* __restrict__ in, u16* __restrict__ out)
{
    const int i = (blockIdx.x * 256 + threadIdx.x) * 8;
    float4 a = *reinterpret_cast<const float4*>(in + i);
    float4 b = *reinterpret_cast<const float4*>(in + i + 4);
    u16x8 o;
    o[0] = f2bf(a.x); o[1] = f2bf(a.y); o[2] = f2bf(a.z); o[3] = f2bf(a.w);
    o[4] = f2bf(b.x); o[5] = f2bf(b.y); o[6] = f2bf(b.z); o[7] = f2bf(b.w);
    *reinterpret_cast<u16x8*>(out + i) = o;
}

// ---------------------------------------------------------------------------
// f32 [K][N] -> bf16 transposed [N][K]
// ---------------------------------------------------------------------------
__global__ __launch_bounds__(256)
void cvt_t_kernel(const float* __restrict__ in, u16* __restrict__ out,
                  int K, int N)
{
    __shared__ float tile[32][33];
    const int kb = blockIdx.x * 32, nb = blockIdx.y * 32;
    const int r = threadIdx.x >> 3, c4 = threadIdx.x & 7;
    float4 v = *reinterpret_cast<const float4*>(&in[(size_t)(kb + r) * N + nb + c4 * 4]);
    tile[r][c4 * 4 + 0] = v.x; tile[r][c4 * 4 + 1] = v.y;
    tile[r][c4 * 4 + 2] = v.z; tile[r][c4 * 4 + 3] = v.w;
    __syncthreads();
    ushort4 o;
    o.x = f2bf(tile[c4 * 4 + 0][r]);
    o.y = f2bf(tile[c4 * 4 + 1][r]);
    o.z = f2bf(tile[c4 * 4 + 2][r]);
    o.w = f2bf(tile[c4 * 4 + 3][r]);
    *reinterpret_cast<ushort4*>(&out[(size_t)(nb + r) * K + kb + c4 * 4]) = o;
}

// ---------------------------------------------------------------------------
// GEMM: C = A @ B, B pre-transposed Bt[N][K].  BM x 128 tile, BK=32, 4 waves,
// double-buffered LDS staged via global_load_lds(16B), 1 barrier / K-step.
// NSPLIT: K split across blockIdx.z, partial written to C + z*M*N.
// QSCALE: scale Q columns (col%192 in [64,128)) by 0.125*log2(e).
// ---------------------------------------------------------------------------
template<int BM, int NSPLIT, bool BIAS, bool RELU, bool QSCALE>
__global__ __launch_bounds__(256)
void gemm_kernel(const u16* __restrict__ A, const u16* __restrict__ Bt,
                 const float* __restrict__ bias, u16* __restrict__ C,
                 int M, int N, int K)
{
    __shared__ u16 As[2][BM][32];
    __shared__ u16 Bs[2][128][32];
    constexpr int AI = BM / 32;
    const int tid  = threadIdx.x;
    const int lane = tid & 63;
    const int wid  = tid >> 6;
    const int wm = wid >> 1, wn = wid & 1;
    const int bm = blockIdx.x, bn = blockIdx.y;
    const int kg = lane >> 4;
    const int lc = lane & 15;
    const int pk = kg ^ (lc & 3);

    f32x4 acc[AI][4];
    #pragma unroll
    for (int i = 0; i < AI; ++i)
        #pragma unroll
        for (int j = 0; j < 4; ++j)
            acc[i][j] = f32x4{0.f, 0.f, 0.f, 0.f};

    const int nk = (K >> 5) / NSPLIT;
    const int kbase = (NSPLIT > 1) ? blockIdx.z * nk : 0;

    auto stage = [&](int kt, int b) {
        int ktg = kbase + kt;
        #pragma unroll
        for (int p = 0; p < BM / 64; ++p) {
            int c = wid * BM + p * 64 + lane;
            int row = c >> 2;
            int ko = ((c & 3) ^ (row & 3)) * 8;
            gld16(A + (size_t)(bm * BM + row) * K + ktg * 32 + ko,
                  &As[b][0][0] + c * 8);
        }
        #pragma unroll
        for (int p = 0; p < 2; ++p) {
            int c = wid * 128 + p * 64 + lane;
            int row = c >> 2;
            int ko = ((c & 3) ^ (row & 3)) * 8;
            gld16(Bt + (size_t)(bn * 128 + row) * K + ktg * 32 + ko,
                  &Bs[b][0][0] + c * 8);
        }
    };

    stage(0, 0);
    __syncthreads();                 // implicit vmcnt(0) drains stage
    for (int kt = 0; kt < nk; ++kt) {
        const int cur = kt & 1;
        if (kt + 1 < nk) stage(kt + 1, cur ^ 1);
        bf16x8 af[AI], bf[4];
        #pragma unroll
        for (int i = 0; i < AI; ++i)
            af[i] = *reinterpret_cast<const bf16x8*>(&As[cur][wm * (BM / 2) + i * 16 + lc][pk * 8]);
        #pragma unroll
        for (int j = 0; j < 4; ++j)
            bf[j] = *reinterpret_cast<const bf16x8*>(&Bs[cur][wn * 64 + j * 16 + lc][pk * 8]);
        #pragma unroll
        for (int j = 0; j < 4; ++j)
            #pragma unroll
            for (int i = 0; i < AI; ++i)
                acc[i][j] = mfma16(af[i], bf[j], acc[i][j]);
        __syncthreads();             // drains next-buf stage + read-done
    }

    u16* Cp = C + (size_t)((NSPLIT > 1) ? blockIdx.z : 0) * M * N;
    #pragma unroll
    for (int i = 0; i < AI; ++i) {
        #pragma unroll
        for (int j = 0; j < 4; ++j) {
            int col = bn * 128 + wn * 64 + j * 16 + lc;
            float bv = 0.f;
            if (BIAS) bv = bias[col];
            float qs = 1.0f;
            if (QSCALE) {
                u32 cm = (u32)col % 192u;
                if (cm >= 64u && cm < 128u) qs = 0.1803368875f;  // 0.125*log2e
            }
            #pragma unroll
            for (int r = 0; r < 4; ++r) {
                int row = bm * BM + wm * (BM / 2) + i * 16 + kg * 4 + r;
                float v = acc[i][j][r] + bv;
                if (RELU) v = v > 0.f ? v : 0.f;
                if (QSCALE) v *= qs;
                Cp[(size_t)row * N + col] = f2bf(v);
            }
        }
    }
}

// ---------------------------------------------------------------------------
// qlo[b][s] = segment start = last p <= s with tokens[p]==start_id, clamped 0
// ---------------------------------------------------------------------------
__global__ __launch_bounds__(256)
void qlo_kernel(const int* __restrict__ tokens, const int* __restrict__ start_id,
                int* __restrict__ qlo)
{
    constexpr int S = 2048;
    __shared__ int part[256];
    __shared__ int pref[256];
    const int b = blockIdx.x, tid = threadIdx.x;
    const int sid = start_id[0];
    const int base = b * S + tid * 8;
    int f[8]; int loc = -1;
    #pragma unroll
    for (int j = 0; j < 8; ++j) {
        f[j] = (tokens[base + j] == sid) ? 1 : 0;
        if (f[j]) loc = tid * 8 + j;
    }
    part[tid] = loc;
    __syncthreads();
    if (tid == 0) {
        int run = -1;
        for (int i = 0; i < 256; ++i) { pref[i] = run; run = max(run, part[i]); }
    }
    __syncthreads();
    int run = pref[tid];
    #pragma unroll
    for (int j = 0; j < 8; ++j) {
        if (f[j]) run = tid * 8 + j;
        qlo[base + j] = max(run, 0);
    }
}

// ---------------------------------------------------------------------------
// flash attention, causal+segment via qlo window [qlo[q], q].
// grid (32, H, B), 256 thr = 4 waves, each wave 16 q-rows.
// kb loop runs only [blockmin(qlo)>>6, qt]  (avg ~2-4 tiles, not qt+1).
// Async stage: issue kb+1 global loads before compute(kb).
// Q pre-scaled by 0.125*log2e  ->  p = exp2(s - m).
// ---------------------------------------------------------------------------
#define MASKVAL -60000.0f
#define MINIT   -30000.0f
__global__ __launch_bounds__(256)
void attn_kernel(const u16* __restrict__ qkv, const int* __restrict__ qloA,
                 u16* __restrict__ attn_out)
{
    constexpr int S = 2048, DQ = 3072;
    __shared__ u16 Ks[64][72];
    __shared__ u16 Vt[64][72];
    __shared__ u16 Pt[4][16][72];
    __shared__ int wm4[4];

    const int tid = threadIdx.x;
    const int lane = tid & 63, w = tid >> 6;
    const int kg = lane >> 4, lc = lane & 15;
    const int qt = blockIdx.x, h = blockIdx.y, b = blockIdx.z;
    const size_t rowbase = (size_t)b * S;
    const int colK = h * 192, colQ = colK + 64, colV = colK + 128;
    const int qrow = qt * 64 + w * 16 + lc;

    bf16x8 qf0, qf1;
    {
        const u16* qp = &qkv[(rowbase + qrow) * DQ + colQ];
        qf0 = *reinterpret_cast<const bf16x8*>(qp + kg * 8);
        qf1 = *reinterpret_cast<const bf16x8*>(qp + 32 + kg * 8);
    }
    const int myqlo = qloA[rowbase + qrow];

    // block-min of qlo -> first k-tile
    int vmin = myqlo;
    #pragma unroll
    for (int m = 1; m < 16; m <<= 1) vmin = min(vmin, __shfl_xor(vmin, m));
    if (lane == 0) wm4[w] = vmin;
    __syncthreads();
    const int kb0 = min(min(wm4[0], wm4[1]), min(wm4[2], wm4[3])) >> 6;

    float m_ = MINIT, l_ = 0.f;
    f32x4 o[4];
    #pragma unroll
    for (int d = 0; d < 4; ++d) o[d] = f32x4{0.f, 0.f, 0.f, 0.f};

    // staging task decomposition (all 256 threads)
    const int kr = tid >> 3, kc = tid & 7;        // K rows kr, kr+32; chunk kc
    const int rpv = tid >> 3, chv = tid & 7;      // V row-pair rpv, col-chunk chv
    uint4 gk0, gk1, gv0, gv1;

    auto issue = [&](int kb) {
        const size_t base = rowbase + (size_t)kb * 64;
        gk0 = *reinterpret_cast<const uint4*>(&qkv[(base + kr) * DQ + colK + kc * 8]);
        gk1 = *reinterpret_cast<const uint4*>(&qkv[(base + 32 + kr) * DQ + colK + kc * 8]);
        const u16* vp = &qkv[(base + rpv * 2) * DQ + colV + chv * 8];
        gv0 = *reinterpret_cast<const uint4*>(vp);
        gv1 = *reinterpret_cast<const uint4*>(vp + DQ);
    };
    auto write_lds = [&]() {
        *reinterpret_cast<uint4*>(&Ks[kr][kc * 8]) = gk0;
        *reinterpret_cast<uint4*>(&Ks[32 + kr][kc * 8]) = gk1;
        u16x8 va = __builtin_bit_cast(u16x8, gv0);
        u16x8 vb = __builtin_bit_cast(u16x8, gv1);
        const int kp = (rpv * 2) ^ (chv << 3);    // 3-bit key: bank floor
        #pragma unroll
        for (int j = 0; j < 8; ++j)
            *reinterpret_cast<u32*>(&Vt[chv * 8 + j][kp]) =
                (u32)va[j] | ((u32)vb[j] << 16);
    };

    issue(kb0);
    for (int kb = kb0; kb <= qt; ++kb) {
        write_lds();
        __syncthreads();
        if (kb < qt) issue(kb + 1);     // overlap next loads with compute

        // S^T = mfma(K, Q): lane holds S[q=qrow][k = kb*64+ks*16+kg*4+r]
        f32x4 sT[4];
        #pragma unroll
        for (int ks = 0; ks < 4; ++ks) {
            bf16x8 kf0 = *reinterpret_cast<const bf16x8*>(&Ks[ks * 16 + lc][kg * 8]);
            bf16x8 kf1 = *reinterpret_cast<const bf16x8*>(&Ks[ks * 16 + lc][32 + kg * 8]);
            f32x4 s = f32x4{0.f, 0.f, 0.f, 0.f};
            s = mfma16(kf0, qf0, s);
            s = mfma16(kf1, qf1, s);
            sT[ks] = s;
        }
        // window mask (scores already scaled via Q)
        const int lo = myqlo - kb * 64, hi = qrow - kb * 64;
        #pragma unroll
        for (int ks = 0; ks < 4; ++ks) {
            #pragma unroll
            for (int r = 0; r < 4; ++r) {
                int kk = ks * 16 + kg * 4 + r;
                bool ok = (kk >= lo) && (kk <= hi);
                sT[ks][r] = ok ? sT[ks][r] : MASKVAL;
            }
        }
        float tm = fmaxf(fmaxf(fmaxf(sT[0][0], sT[0][1]), fmaxf(sT[0][2], sT[0][3])),
                         fmaxf(fmaxf(sT[1][0], sT[1][1]), fmaxf(sT[1][2], sT[1][3])));
        tm = fmaxf(tm, fmaxf(fmaxf(fmaxf(sT[2][0], sT[2][1]), fmaxf(sT[2][2], sT[2][3])),
                             fmaxf(fmaxf(sT[3][0], sT[3][1]), fmaxf(sT[3][2], sT[3][3]))));
        tm = fmaxf(tm, __shfl_xor(tm, 16));
        tm = fmaxf(tm, __shfl_xor(tm, 32));
        float mn = fmaxf(m_, tm);
        float al = exp2f(m_ - mn);
        m_ = mn;
        float ps = 0.f;
        #pragma unroll
        for (int ks = 0; ks < 4; ++ks) {
            ushort4 pw;
            float p0 = exp2f(sT[ks][0] - m_); ps += p0; pw.x = f2bf(p0);
            float p1 = exp2f(sT[ks][1] - m_); ps += p1; pw.y = f2bf(p1);
            float p2 = exp2f(sT[ks][2] - m_); ps += p2; pw.z = f2bf(p2);
            float p3 = exp2f(sT[ks][3] - m_); ps += p3; pw.w = f2bf(p3);
            *reinterpret_cast<ushort4*>(&Pt[w][lc][ks * 16 + kg * 4]) = pw;
        }
        ps += __shfl_xor(ps, 16);
        ps += __shfl_xor(ps, 32);
        l_ = l_ * al + ps;
        float alr[4];
        #pragma unroll
        for (int r = 0; r < 4; ++r) alr[r] = __shfl(al, kg * 4 + r);
        #pragma unroll
        for (int d = 0; d < 4; ++d)
            #pragma unroll
            for (int r = 0; r < 4; ++r) o[d][r] *= alr[r];

        // O += P V  (Pt per-wave same-wave RAW; Vt 3-bit-XOR layout)
        #pragma unroll
        for (int kf = 0; kf < 2; ++kf) {
            bf16x8 pf = *reinterpret_cast<const bf16x8*>(&Pt[w][lc][kf * 32 + kg * 8]);
            #pragma unroll
            for (int d = 0; d < 4; ++d) {
                int vrow = d * 16 + lc;
                int b3 = (kf * 4 + kg) ^ ((vrow >> 3) & 7);
                bf16x8 vf = *reinterpret_cast<const bf16x8*>(&Vt[vrow][b3 * 8]);
                o[d] = mfma16(pf, vf, o[d]);
            }
        }
        __syncthreads();   // done reading Ks/Vt before next overwrite
    }

    float lr[4];
    #pragma unroll
    for (int r = 0; r < 4; ++r) lr[r] = __shfl(l_, kg * 4 + r);
    #pragma unroll
    for (int d = 0; d < 4; ++d)
        #pragma unroll
        for (int r = 0; r < 4; ++r) {
            float v = o[d][r] / fmaxf(lr[r], 1e-20f);
            int qo = qt * 64 + w * 16 + kg * 4 + r;
            attn_out[(rowbase + qo) * 1024 + h * 64 + d * 16 + lc] = f2bf(v);
        }
}

// ---------------------------------------------------------------------------
// LayerNorm + residual.  SPLIT: in = in[idx] + in2[idx] (split-K partials).
// ---------------------------------------------------------------------------
template<bool SPLIT, bool WRITE_BF>
__global__ __launch_bounds__(256)
void ln_kernel(const u16* __restrict__ in, const u16* __restrict__ in2,
               const float* __restrict__ gam, const float* __restrict__ bet,
               const float* res, float* out_f, u16* __restrict__ out_bf)
{
    const int row = blockIdx.x;
    const int tid = threadIdx.x;
    const int lane = tid & 63, w = tid >> 6;
    __shared__ float red1[4], red2[4];

    const size_t base = (size_t)row * 1024 + tid * 4;
    ushort4 xv = *reinterpret_cast<const ushort4*>(in + base);
    float x0 = bf2f(xv.x), x1 = bf2f(xv.y), x2 = bf2f(xv.z), x3 = bf2f(xv.w);
    if constexpr (SPLIT) {
        ushort4 yv = *reinterpret_cast<const ushort4*>(in2 + base);
        x0 += bf2f(yv.x); x1 += bf2f(yv.y); x2 += bf2f(yv.z); x3 += bf2f(yv.w);
    }

    float s = x0 + x1 + x2 + x3;
    #pragma unroll
    for (int m = 1; m < 64; m <<= 1) s += __shfl_xor(s, m);
    if (lane == 0) red1[w] = s;
    __syncthreads();
    float mu = (red1[0] + red1[1] + red1[2] + red1[3]) * (1.0f / 1024.0f);

    float d0 = x0 - mu, d1 = x1 - mu, d2 = x2 - mu, d3 = x3 - mu;
    float q = d0 * d0 + d1 * d1 + d2 * d2 + d3 * d3;
    #pragma unroll
    for (int m = 1; m < 64; m <<= 1) q += __shfl_xor(q, m);
    if (lane == 0) red2[w] = q;
    __syncthreads();
    float var = (red2[0] + red2[1] + red2[2] + red2[3]) * (1.0f / 1024.0f);
    float rs = rsqrtf(var + 1e-6f);

    float dd[4] = {d0, d1, d2, d3};
    #pragma unroll
    for (int e = 0; e < 4; ++e) {
        int col = tid * 4 + e;
        size_t idx = (size_t)row * 1024 + col;
        float y = dd[e] * rs * gam[col] + bet[col];
        float ov = y + res[idx];
        out_f[idx] = ov;
        if constexpr (WRITE_BF) out_bf[idx] = f2bf(ov);
    }
}

// ---------------------------------------------------------------------------
// Workspace (peak 48 MB):
//   [0,8M)    XB (A) -> WUBt (E) -> WDBt (F)
//   [8,14M)   KBt (A) -> WOBt [8,10M) (C) -> x_bf (D-E) -> t2 (F-G)
//   [14,38M)  qkv (A-B);  after attn: C partials [16,32M)
//   [39845888] qlo 16KB (through attn)
//   [40,48M)  attn_o (B-C)
//   [16,48M)  hbuf (E-F)
// d_out (f32 16MB) holds residual x from D to G.
// ---------------------------------------------------------------------------
extern "C" void kernel_launch(void* const* d_in, const int* in_sizes, int n_in,
                              void* d_out, int out_size, void* d_ws, size_t ws_size,
                              hipStream_t stream)
{
    const float* x_emb = (const float*)d_in[0];
    const int* tokens  = (const int*)d_in[1];
    const float* KQV   = (const float*)d_in[2];
    const float* WO    = (const float*)d_in[3];
    const float* W_up  = (const float*)d_in[4];
    const float* b_up  = (const float*)d_in[5];
    const float* W_dn  = (const float*)d_in[6];
    const float* b_dn  = (const float*)d_in[7];
    const float* g1    = (const float*)d_in[8];
    const float* be1   = (const float*)d_in[9];
    const float* g2    = (const float*)d_in[10];
    const float* be2   = (const float*)d_in[11];
    const int* start   = (const int*)d_in[12];

    char* ws = (char*)d_ws;
    u16* XB     = (u16*)(ws + 0);
    u16* KBt    = (u16*)(ws + 8388608);
    u16* qkv    = (u16*)(ws + 14680064);
    int* qloA   = (int*)(ws + 39845888);
    u16* attn_o = (u16*)(ws + 41943040);
    u16* WOBt   = (u16*)(ws + 8388608);
    u16* cpart  = (u16*)(ws + 16777216);    // 2 x 8MB bf16 partials (C)
    u16* x_bf   = (u16*)(ws + 8388608);
    u16* WUBt   = (u16*)(ws + 0);
    u16* hbuf   = (u16*)(ws + 16777216);
    u16* WDBt   = (u16*)(ws + 0);
    u16* t2     = (u16*)(ws + 8388608);
    float* x_f  = (float*)d_out;
    float* outp = (float*)d_out;

    cvt_kernel<<<2048, 256, 0, stream>>>(x_emb, XB);
    cvt_t_kernel<<<dim3(32, 96), 256, 0, stream>>>(KQV, KBt, 1024, 3072);
    qlo_kernel<<<2, 256, 0, stream>>>(tokens, start, qloA);
    // A. qkv = x_embeds @ KQV   (Q columns pre-scaled)
    gemm_kernel<128, 1, false, false, true><<<dim3(32, 24), 256, 0, stream>>>(XB, KBt, nullptr, qkv, 4096, 3072, 1024);
    cvt_t_kernel<<<dim3(32, 32), 256, 0, stream>>>(WO, WOBt, 1024, 1024);
    // B. attention (segment-windowed)
    attn_kernel<<<dim3(32, 16, 2), 256, 0, stream>>>(qkv, qloA, attn_o);
    // C. cpart[z] = attn_o @ WO (split-K=2)
    gemm_kernel<128, 2, false, false, false><<<dim3(32, 8, 2), 256, 0, stream>>>(attn_o, WOBt, nullptr, cpart, 4096, 1024, 1024);
    // D. x = LN1(cpart0+cpart1) + x_embeds
    ln_kernel<true, true><<<4096, 256, 0, stream>>>(cpart, cpart + 4194304, g1, be1, x_emb, x_f, x_bf);
    cvt_t_kernel<<<dim3(32, 128), 256, 0, stream>>>(W_up, WUBt, 1024, 4096);
    // E. h = relu(x @ W_up + b_up)
    gemm_kernel<128, 1, true, true, false><<<dim3(32, 32), 256, 0, stream>>>(x_bf, WUBt, b_up, hbuf, 4096, 4096, 1024);
    cvt_t_kernel<<<dim3(128, 32), 256, 0, stream>>>(W_dn, WDBt, 4096, 1024);
    // F. t2 = h @ W_down + b_down
    gemm_kernel<64, 1, true, false, false><<<dim3(64, 8), 256, 0, stream>>>(hbuf, WDBt, b_dn, t2, 4096, 1024, 4096);
    // G. out = LN2(t2) + x
    ln_kernel<false, false><<<4096, 256, 0, stream>>>(t2, nullptr, g2, be2, x_f, outp, nullptr);
}

// Round 7
// 243.146 us; speedup vs baseline: 2.1586x; 1.0365x over previous
//
#include <hip/hip_runtime.h>

typedef unsigned short u16;
typedef unsigned int u32;
typedef __bf16 bf16_t;
typedef bf16_t bf16x8 __attribute__((ext_vector_type(8)));
typedef u16 u16x8 __attribute__((ext_vector_type(8)));
typedef float f32x4 __attribute__((ext_vector_type(4)));

__device__ __forceinline__ float bf2f(u16 u) {
    union { float f; unsigned i; } c; c.i = ((unsigned)u) << 16; return c.f;
}
__device__ __forceinline__ u16 f2bf(float f) {
    return __builtin_bit_cast(u16, (bf16_t)f);   // native v_cvt (RTNE)
}
__device__ __forceinline__ f32x4 mfma16(bf16x8 a, bf16x8 b, f32x4 c) {
    return __builtin_amdgcn_mfma_f32_16x16x32_bf16(a, b, c, 0, 0, 0);
}
__device__ __forceinline__ void gld16(const u16* g, u16* l) {
    __builtin_amdgcn_global_load_lds(
        (const __attribute__((address_space(1))) void*)g,
        (__attribute__((address_space(3))) void*)l, 16, 0, 0);
}

// ---------------------------------------------------------------------------
// f32 -> bf16, 8 elems/thread
// ---------------------------------------------------------------------------
__global__ __launch_bounds__(256)
void cvt_kernel(const float* __restrict__ in, u16* __restrict__ out)
{
    const int i = (blockIdx.x * 256 + threadIdx.x) * 8;
    float4 a = *reinterpret_cast<const float4*>(in + i);
    float4 b = *reinterpret_cast<const float4*>(in + i + 4);
    u16x8 o;
    o[0] = f2bf(a.x); o[1] = f2bf(a.y); o[2] = f2bf(a.z); o[3] = f2bf(a.w);
    o[4] = f2bf(b.x); o[5] = f2bf(b.y); o[6] = f2bf(b.z); o[7] = f2bf(b.w);
    *reinterpret_cast<u16x8*>(out + i) = o;
}

// ---------------------------------------------------------------------------
// f32 [K][N] -> bf16 transposed [N][K]
// ---------------------------------------------------------------------------
__global__ __launch_bounds__(256)
void cvt_t_kernel(const float* __restrict__ in, u16* __restrict__ out,
                  int K, int N)
{
    __shared__ float tile[32][33];
    const int kb = blockIdx.x * 32, nb = blockIdx.y * 32;
    const int r = threadIdx.x >> 3, c4 = threadIdx.x & 7;
    float4 v = *reinterpret_cast<const float4*>(&in[(size_t)(kb + r) * N + nb + c4 * 4]);
    tile[r][c4 * 4 + 0] = v.x; tile[r][c4 * 4 + 1] = v.y;
    tile[r][c4 * 4 + 2] = v.z; tile[r][c4 * 4 + 3] = v.w;
    __syncthreads();
    ushort4 o;
    o.x = f2bf(tile[c4 * 4 + 0][r]);
    o.y = f2bf(tile[c4 * 4 + 1][r]);
    o.z = f2bf(tile[c4 * 4 + 2][r]);
    o.w = f2bf(tile[c4 * 4 + 3][r]);
    *reinterpret_cast<ushort4*>(&out[(size_t)(nb + r) * K + kb + c4 * 4]) = o;
}

// ---------------------------------------------------------------------------
// GEMM: C = A @ B, B pre-transposed Bt[N][K].  BM x 128 tile, BK=32, 4 waves,
// double-buffered LDS via global_load_lds(16B), 1 barrier / K-step.
// Chunk swizzle key f(row) = (row + row/4) & 3  -> b128 frag reads at the
// wave64 bank floor (8 lanes/16B-slot).  Staging pre-applies inverse on the
// global source; LDS stays linear (global_load_lds constraint).
// NSPLIT: K split across blockIdx.z, partial to C + z*M*N; bias only z==0.
// QSCALE: scale Q columns (col%192 in [64,128)) by 0.125*log2(e).
// ---------------------------------------------------------------------------
template<int BM, int NSPLIT, bool BIAS, bool RELU, bool QSCALE>
__global__ __launch_bounds__(256)
void gemm_kernel(const u16* __restrict__ A, const u16* __restrict__ Bt,
                 const float* __restrict__ bias, u16* __restrict__ C,
                 int M, int N, int K)
{
    __shared__ u16 As[2][BM][32];
    __shared__ u16 Bs[2][128][32];
    constexpr int AI = BM / 32;
    const int tid  = threadIdx.x;
    const int lane = tid & 63;
    const int wid  = tid >> 6;
    const int wm = wid >> 1, wn = wid & 1;
    const int bm = blockIdx.x, bn = blockIdx.y;
    const int kg = lane >> 4;
    const int lc = lane & 15;
    const int pk = kg ^ ((lc + (lc >> 2)) & 3);   // frag-read chunk

    f32x4 acc[AI][4];
    #pragma unroll
    for (int i = 0; i < AI; ++i)
        #pragma unroll
        for (int j = 0; j < 4; ++j)
            acc[i][j] = f32x4{0.f, 0.f, 0.f, 0.f};

    const int nk = (K >> 5) / NSPLIT;
    const int kbase = (NSPLIT > 1) ? blockIdx.z * nk : 0;

    auto stage = [&](int kt, int b) {
        int ktg = kbase + kt;
        #pragma unroll
        for (int p = 0; p < BM / 64; ++p) {
            int c = wid * BM + p * 64 + lane;
            int ko = (((c & 3) ^ (((c >> 2) + (c >> 4)) & 3))) * 8;
            gld16(A + (size_t)(bm * BM + (c >> 2)) * K + ktg * 32 + ko,
                  &As[b][0][0] + c * 8);
        }
        #pragma unroll
        for (int p = 0; p < 2; ++p) {
            int c = wid * 128 + p * 64 + lane;
            int ko = (((c & 3) ^ (((c >> 2) + (c >> 4)) & 3))) * 8;
            gld16(Bt + (size_t)(bn * 128 + (c >> 2)) * K + ktg * 32 + ko,
                  &Bs[b][0][0] + c * 8);
        }
    };

    stage(0, 0);
    __syncthreads();
    for (int kt = 0; kt < nk; ++kt) {
        const int cur = kt & 1;
        if (kt + 1 < nk) stage(kt + 1, cur ^ 1);
        bf16x8 af[AI], bf[4];
        #pragma unroll
        for (int i = 0; i < AI; ++i)
            af[i] = *reinterpret_cast<const bf16x8*>(&As[cur][wm * (BM / 2) + i * 16 + lc][pk * 8]);
        #pragma unroll
        for (int j = 0; j < 4; ++j)
            bf[j] = *reinterpret_cast<const bf16x8*>(&Bs[cur][wn * 64 + j * 16 + lc][pk * 8]);
        #pragma unroll
        for (int j = 0; j < 4; ++j)
            #pragma unroll
            for (int i = 0; i < AI; ++i)
                acc[i][j] = mfma16(af[i], bf[j], acc[i][j]);
        __syncthreads();
    }

    u16* Cp = C + (size_t)((NSPLIT > 1) ? blockIdx.z : 0) * M * N;
    const bool addb = BIAS && (NSPLIT == 1 || blockIdx.z == 0);
    #pragma unroll
    for (int i = 0; i < AI; ++i) {
        #pragma unroll
        for (int j = 0; j < 4; ++j) {
            int col = bn * 128 + wn * 64 + j * 16 + lc;
            float bv = addb ? bias[col] : 0.f;
            float qs = 1.0f;
            if (QSCALE) {
                u32 cm = (u32)col % 192u;
                if (cm >= 64u && cm < 128u) qs = 0.1803368875f;  // 0.125*log2e
            }
            #pragma unroll
            for (int r = 0; r < 4; ++r) {
                int row = bm * BM + wm * (BM / 2) + i * 16 + kg * 4 + r;
                float v = acc[i][j][r] + bv;
                if (RELU) v = v > 0.f ? v : 0.f;
                if (QSCALE) v *= qs;
                Cp[(size_t)row * N + col] = f2bf(v);
            }
        }
    }
}

// ---------------------------------------------------------------------------
// qlo[b][s] = last p <= s with tokens[p]==start_id, clamped 0
// ---------------------------------------------------------------------------
__global__ __launch_bounds__(256)
void qlo_kernel(const int* __restrict__ tokens, const int* __restrict__ start_id,
                int* __restrict__ qlo)
{
    constexpr int S = 2048;
    __shared__ int part[256];
    __shared__ int pref[256];
    const int b = blockIdx.x, tid = threadIdx.x;
    const int sid = start_id[0];
    const int base = b * S + tid * 8;
    int f[8]; int loc = -1;
    #pragma unroll
    for (int j = 0; j < 8; ++j) {
        f[j] = (tokens[base + j] == sid) ? 1 : 0;
        if (f[j]) loc = tid * 8 + j;
    }
    part[tid] = loc;
    __syncthreads();
    if (tid == 0) {
        int run = -1;
        for (int i = 0; i < 256; ++i) { pref[i] = run; run = max(run, part[i]); }
    }
    __syncthreads();
    int run = pref[tid];
    #pragma unroll
    for (int j = 0; j < 8; ++j) {
        if (f[j]) run = tid * 8 + j;
        qlo[base + j] = max(run, 0);
    }
}

// ---------------------------------------------------------------------------
// flash attention, causal+segment via qlo window [qlo[q], q].
// ---------------------------------------------------------------------------
#define MASKVAL -60000.0f
#define MINIT   -30000.0f
__global__ __launch_bounds__(256)
void attn_kernel(const u16* __restrict__ qkv, const int* __restrict__ qloA,
                 u16* __restrict__ attn_out)
{
    constexpr int S = 2048, DQ = 3072;
    __shared__ u16 Ks[64][72];
    __shared__ u16 Vt[64][72];
    __shared__ u16 Pt[4][16][72];
    __shared__ int wm4[4];

    const int tid = threadIdx.x;
    const int lane = tid & 63, w = tid >> 6;
    const int kg = lane >> 4, lc = lane & 15;
    const int qt = blockIdx.x, h = blockIdx.y, b = blockIdx.z;
    const size_t rowbase = (size_t)b * S;
    const int colK = h * 192, colQ = colK + 64, colV = colK + 128;
    const int qrow = qt * 64 + w * 16 + lc;

    bf16x8 qf0, qf1;
    {
        const u16* qp = &qkv[(rowbase + qrow) * DQ + colQ];
        qf0 = *reinterpret_cast<const bf16x8*>(qp + kg * 8);
        qf1 = *reinterpret_cast<const bf16x8*>(qp + 32 + kg * 8);
    }
    const int myqlo = qloA[rowbase + qrow];

    int vmin = myqlo;
    #pragma unroll
    for (int m = 1; m < 16; m <<= 1) vmin = min(vmin, __shfl_xor(vmin, m));
    if (lane == 0) wm4[w] = vmin;
    __syncthreads();
    const int kb0 = min(min(wm4[0], wm4[1]), min(wm4[2], wm4[3])) >> 6;

    float m_ = MINIT, l_ = 0.f;
    f32x4 o[4];
    #pragma unroll
    for (int d = 0; d < 4; ++d) o[d] = f32x4{0.f, 0.f, 0.f, 0.f};

    const int kr = tid >> 3, kc = tid & 7;
    const int rpv = tid >> 3, chv = tid & 7;
    uint4 gk0, gk1, gv0, gv1;

    auto issue = [&](int kb) {
        const size_t base = rowbase + (size_t)kb * 64;
        gk0 = *reinterpret_cast<const uint4*>(&qkv[(base + kr) * DQ + colK + kc * 8]);
        gk1 = *reinterpret_cast<const uint4*>(&qkv[(base + 32 + kr) * DQ + colK + kc * 8]);
        const u16* vp = &qkv[(base + rpv * 2) * DQ + colV + chv * 8];
        gv0 = *reinterpret_cast<const uint4*>(vp);
        gv1 = *reinterpret_cast<const uint4*>(vp + DQ);
    };
    auto write_lds = [&]() {
        *reinterpret_cast<uint4*>(&Ks[kr][kc * 8]) = gk0;
        *reinterpret_cast<uint4*>(&Ks[32 + kr][kc * 8]) = gk1;
        u16x8 va = __builtin_bit_cast(u16x8, gv0);
        u16x8 vb = __builtin_bit_cast(u16x8, gv1);
        const int kp = (rpv * 2) ^ (chv << 3);
        #pragma unroll
        for (int j = 0; j < 8; ++j)
            *reinterpret_cast<u32*>(&Vt[chv * 8 + j][kp]) =
                (u32)va[j] | ((u32)vb[j] << 16);
    };

    issue(kb0);
    for (int kb = kb0; kb <= qt; ++kb) {
        write_lds();
        __syncthreads();
        if (kb < qt) issue(kb + 1);

        f32x4 sT[4];
        #pragma unroll
        for (int ks = 0; ks < 4; ++ks) {
            bf16x8 kf0 = *reinterpret_cast<const bf16x8*>(&Ks[ks * 16 + lc][kg * 8]);
            bf16x8 kf1 = *reinterpret_cast<const bf16x8*>(&Ks[ks * 16 + lc][32 + kg * 8]);
            f32x4 s = f32x4{0.f, 0.f, 0.f, 0.f};
            s = mfma16(kf0, qf0, s);
            s = mfma16(kf1, qf1, s);
            sT[ks] = s;
        }
        const int lo = myqlo - kb * 64, hi = qrow - kb * 64;
        #pragma unroll
        for (int ks = 0; ks < 4; ++ks) {
            #pragma unroll
            for (int r = 0; r < 4; ++r) {
                int kk = ks * 16 + kg * 4 + r;
                bool ok = (kk >= lo) && (kk <= hi);
                sT[ks][r] = ok ? sT[ks][r] : MASKVAL;
            }
        }
        float tm = fmaxf(fmaxf(fmaxf(sT[0][0], sT[0][1]), fmaxf(sT[0][2], sT[0][3])),
                         fmaxf(fmaxf(sT[1][0], sT[1][1]), fmaxf(sT[1][2], sT[1][3])));
        tm = fmaxf(tm, fmaxf(fmaxf(fmaxf(sT[2][0], sT[2][1]), fmaxf(sT[2][2], sT[2][3])),
                             fmaxf(fmaxf(sT[3][0], sT[3][1]), fmaxf(sT[3][2], sT[3][3]))));
        tm = fmaxf(tm, __shfl_xor(tm, 16));
        tm = fmaxf(tm, __shfl_xor(tm, 32));
        float mn = fmaxf(m_, tm);
        float al = exp2f(m_ - mn);
        m_ = mn;
        float ps = 0.f;
        #pragma unroll
        for (int ks = 0; ks < 4; ++ks) {
            ushort4 pw;
            float p0 = exp2f(sT[ks][0] - m_); ps += p0; pw.x = f2bf(p0);
            float p1 = exp2f(sT[ks][1] - m_); ps += p1; pw.y = f2bf(p1);
            float p2 = exp2f(sT[ks][2] - m_); ps += p2; pw.z = f2bf(p2);
            float p3 = exp2f(sT[ks][3] - m_); ps += p3; pw.w = f2bf(p3);
            *reinterpret_cast<ushort4*>(&Pt[w][lc][ks * 16 + kg * 4]) = pw;
        }
        ps += __shfl_xor(ps, 16);
        ps += __shfl_xor(ps, 32);
        l_ = l_ * al + ps;
        float alr[4];
        #pragma unroll
        for (int r = 0; r < 4; ++r) alr[r] = __shfl(al, kg * 4 + r);
        #pragma unroll
        for (int d = 0; d < 4; ++d)
            #pragma unroll
            for (int r = 0; r < 4; ++r) o[d][r] *= alr[r];

        #pragma unroll
        for (int kf = 0; kf < 2; ++kf) {
            bf16x8 pf = *reinterpret_cast<const bf16x8*>(&Pt[w][lc][kf * 32 + kg * 8]);
            #pragma unroll
            for (int d = 0; d < 4; ++d) {
                int vrow = d * 16 + lc;
                int b3 = (kf * 4 + kg) ^ ((vrow >> 3) & 7);
                bf16x8 vf = *reinterpret_cast<const bf16x8*>(&Vt[vrow][b3 * 8]);
                o[d] = mfma16(pf, vf, o[d]);
            }
        }
        __syncthreads();
    }

    float lr[4];
    #pragma unroll
    for (int r = 0; r < 4; ++r) lr[r] = __shfl(l_, kg * 4 + r);
    #pragma unroll
    for (int d = 0; d < 4; ++d)
        #pragma unroll
        for (int r = 0; r < 4; ++r) {
            float v = o[d][r] / fmaxf(lr[r], 1e-20f);
            int qo = qt * 64 + w * 16 + kg * 4 + r;
            attn_out[(rowbase + qo) * 1024 + h * 64 + d * 16 + lc] = f2bf(v);
        }
}

// ---------------------------------------------------------------------------
// LayerNorm + residual.  Sums NSPL bf16 partials (stride 4M elems) first.
// ---------------------------------------------------------------------------
template<int NSPL, bool WRITE_BF>
__global__ __launch_bounds__(256)
void ln_kernel(const u16* __restrict__ in, const float* __restrict__ gam,
               const float* __restrict__ bet, const float* res,
               float* out_f, u16* __restrict__ out_bf)
{
    const int row = blockIdx.x;
    const int tid = threadIdx.x;
    const int lane = tid & 63, w = tid >> 6;
    __shared__ float red1[4], red2[4];

    const size_t base = (size_t)row * 1024 + tid * 4;
    float x0 = 0.f, x1 = 0.f, x2 = 0.f, x3 = 0.f;
    #pragma unroll
    for (int sp = 0; sp < NSPL; ++sp) {
        ushort4 xv = *reinterpret_cast<const ushort4*>(in + (size_t)sp * 4194304 + base);
        x0 += bf2f(xv.x); x1 += bf2f(xv.y); x2 += bf2f(xv.z); x3 += bf2f(xv.w);
    }

    float s = x0 + x1 + x2 + x3;
    #pragma unroll
    for (int m = 1; m < 64; m <<= 1) s += __shfl_xor(s, m);
    if (lane == 0) red1[w] = s;
    __syncthreads();
    float mu = (red1[0] + red1[1] + red1[2] + red1[3]) * (1.0f / 1024.0f);

    float d0 = x0 - mu, d1 = x1 - mu, d2 = x2 - mu, d3 = x3 - mu;
    float q = d0 * d0 + d1 * d1 + d2 * d2 + d3 * d3;
    #pragma unroll
    for (int m = 1; m < 64; m <<= 1) q += __shfl_xor(q, m);
    if (lane == 0) red2[w] = q;
    __syncthreads();
    float var = (red2[0] + red2[1] + red2[2] + red2[3]) * (1.0f / 1024.0f);
    float rs = rsqrtf(var + 1e-6f);

    float dd[4] = {d0, d1, d2, d3};
    #pragma unroll
    for (int e = 0; e < 4; ++e) {
        int col = tid * 4 + e;
        size_t idx = (size_t)row * 1024 + col;
        float y = dd[e] * rs * gam[col] + bet[col];
        float ov = y + res[idx];
        out_f[idx] = ov;
        if constexpr (WRITE_BF) out_bf[idx] = f2bf(ov);
    }
}

// ---------------------------------------------------------------------------
// Workspace timeline (MiB offsets):
//   XB   [0,8)   x_emb bf16 (start-A)  -> WOBt [0,2) (A-C) -> x_bf [0,8) (D-E)
//                                      -> WDBt [0,8) (after E-F)
//   qkv  [8,32)  (A-B)  -> cpart c0 [8,16) c1 [16,24) (C-D) -> hbuf [8,40) (E-F)
//   attn_o [32,40) (B-C)
//   KBt  [40,46) + qlo [46M] (start-B) -> WUBt [40,48) (after B - E)
//   F partials: p0 [40,48), p1.. [48, 48+8(ns-1))  — ns chosen by ws_size
// d_out (f32 16MB) holds residual x from D to G.
// ---------------------------------------------------------------------------
extern "C" void kernel_launch(void* const* d_in, const int* in_sizes, int n_in,
                              void* d_out, int out_size, void* d_ws, size_t ws_size,
                              hipStream_t stream)
{
    const float* x_emb = (const float*)d_in[0];
    const int* tokens  = (const int*)d_in[1];
    const float* KQV   = (const float*)d_in[2];
    const float* WO    = (const float*)d_in[3];
    const float* W_up  = (const float*)d_in[4];
    const float* b_up  = (const float*)d_in[5];
    const float* W_dn  = (const float*)d_in[6];
    const float* b_dn  = (const float*)d_in[7];
    const float* g1    = (const float*)d_in[8];
    const float* be1   = (const float*)d_in[9];
    const float* g2    = (const float*)d_in[10];
    const float* be2   = (const float*)d_in[11];
    const int* start   = (const int*)d_in[12];

    const size_t MiB = 1048576;
    char* ws = (char*)d_ws;
    u16* XB     = (u16*)(ws + 0);
    u16* qkv    = (u16*)(ws + 8 * MiB);
    u16* attn_o = (u16*)(ws + 32 * MiB);
    u16* KBt    = (u16*)(ws + 40 * MiB);
    int* qloA   = (int*)(ws + 46 * MiB);
    u16* WOBt   = (u16*)(ws + 0);
    u16* cpart  = (u16*)(ws + 8 * MiB);
    u16* x_bf   = (u16*)(ws + 0);
    u16* WUBt   = (u16*)(ws + 40 * MiB);
    u16* hbuf   = (u16*)(ws + 8 * MiB);
    u16* WDBt   = (u16*)(ws + 0);
    u16* fpart  = (u16*)(ws + 40 * MiB);
    float* x_f  = (float*)d_out;
    float* outp = (float*)d_out;

    cvt_kernel<<<2048, 256, 0, stream>>>(x_emb, XB);
    cvt_t_kernel<<<dim3(32, 96), 256, 0, stream>>>(KQV, KBt, 1024, 3072);
    qlo_kernel<<<2, 256, 0, stream>>>(tokens, start, qloA);
    // A. qkv = x_embeds @ KQV (Q pre-scaled)
    gemm_kernel<128, 1, false, false, true><<<dim3(32, 24), 256, 0, stream>>>(XB, KBt, nullptr, qkv, 4096, 3072, 1024);
    cvt_t_kernel<<<dim3(32, 32), 256, 0, stream>>>(WO, WOBt, 1024, 1024);
    // B. attention
    attn_kernel<<<dim3(32, 16, 2), 256, 0, stream>>>(qkv, qloA, attn_o);
    cvt_t_kernel<<<dim3(32, 128), 256, 0, stream>>>(W_up, WUBt, 1024, 4096);
    // C. cpart = attn_o @ WO (split-K=2)
    gemm_kernel<128, 2, false, false, false><<<dim3(32, 8, 2), 256, 0, stream>>>(attn_o, WOBt, nullptr, cpart, 4096, 1024, 1024);
    // D. x = LN1(c0+c1) + x_embeds
    ln_kernel<2, true><<<4096, 256, 0, stream>>>(cpart, g1, be1, x_emb, x_f, x_bf);
    // E. h = relu(x @ W_up + b_up)
    gemm_kernel<128, 1, true, true, false><<<dim3(32, 32), 256, 0, stream>>>(x_bf, WUBt, b_up, hbuf, 4096, 4096, 1024);
    cvt_t_kernel<<<dim3(128, 32), 256, 0, stream>>>(W_dn, WDBt, 4096, 1024);
    // F. fpart = h @ W_down + b_down (split-K adaptive on ws_size)
    if (ws_size >= 72 * MiB) {
        gemm_kernel<128, 4, true, false, false><<<dim3(32, 8, 4), 256, 0, stream>>>(hbuf, WDBt, b_dn, fpart, 4096, 1024, 4096);
        ln_kernel<4, false><<<4096, 256, 0, stream>>>(fpart, g2, be2, x_f, outp, nullptr);
    } else if (ws_size >= 56 * MiB) {
        gemm_kernel<128, 2, true, false, false><<<dim3(32, 8, 2), 256, 0, stream>>>(hbuf, WDBt, b_dn, fpart, 4096, 1024, 4096);
        ln_kernel<2, false><<<4096, 256, 0, stream>>>(fpart, g2, be2, x_f, outp, nullptr);
    } else {
        gemm_kernel<64, 1, true, false, false><<<dim3(64, 8), 256, 0, stream>>>(hbuf, WDBt, b_dn, fpart, 4096, 1024, 4096);
        ln_kernel<1, false><<<4096, 256, 0, stream>>>(fpart, g2, be2, x_f, outp, nullptr);
    }
}